// Round 9
// baseline (7234.550 us; speedup 1.0000x reference)
//
#include <hip/hip_runtime.h>
#include <hip/hip_bf16.h>
#include <stdint.h>

#define NB 256
#define PERIOD 30

typedef __bf16  bf16x8 __attribute__((ext_vector_type(8)));
typedef float   f32x4  __attribute__((ext_vector_type(4)));
typedef unsigned int uint4v __attribute__((ext_vector_type(4)));

__device__ __forceinline__ float frcp(float x){ return __builtin_amdgcn_rcpf(x); }

// tanh(x) = 1 - 2/(exp(2x)+1)
__device__ __forceinline__ float fast_tanh(float x){
  float e = __expf(2.0f*x);
  return fmaf(-2.0f, frcp(e + 1.0f), 1.0f);
}

__device__ __forceinline__ unsigned int f2bfbits(float x){
  union { __hip_bfloat16 b; unsigned short u; } v;
  v.b = __float2bfloat16(x);          // RNE, matches XLA convert
  return (unsigned int)v.u;
}
__device__ __forceinline__ unsigned int pack2bf(float lo, float hi){
  return f2bfbits(lo) | (f2bfbits(hi) << 16);
}

// Threefry-2x32, 20 rounds, key = (0, 42)
__device__ __forceinline__ void threefry2x32_k42(uint32_t x0, uint32_t x1,
                                                 uint32_t& o0, uint32_t& o1){
  const uint32_t ks0 = 0u, ks1 = 42u, ks2 = 0u ^ 42u ^ 0x1BD11BDAu;
  x0 += ks0; x1 += ks1;
#define TFR(rot) { x0 += x1; x1 = (x1 << (rot)) | (x1 >> (32 - (rot))); x1 ^= x0; }
  TFR(13) TFR(15) TFR(26) TFR(6)
  x0 += ks1; x1 += ks2 + 1u;
  TFR(17) TFR(29) TFR(16) TFR(24)
  x0 += ks2; x1 += ks0 + 2u;
  TFR(13) TFR(15) TFR(26) TFR(6)
  x0 += ks0; x1 += ks1 + 3u;
  TFR(17) TFR(29) TFR(16) TFR(24)
  x0 += ks1; x1 += ks2 + 4u;
  TFR(13) TFR(15) TFR(26) TFR(6)
  x0 += ks2; x1 += ks0 + 5u;
#undef TFR
  o0 = x0; o1 = x1;
}

// Mirror jax.random.normal f32 (XLA erfinv polynomial)
__device__ __forceinline__ float normal_from_bits(uint32_t bits){
  float f = __uint_as_float((bits >> 9) | 0x3f800000u) - 1.0f;
  const float lo = -0.99999994f;
  float u = fmaf(f, 2.0f, lo);
  u = fmaxf(u, lo);
  float w = -log1pf(-u*u);
  float p;
  if (w < 5.0f){
    float ww = w - 2.5f;
    p = 2.81022636e-08f;
    p = fmaf(p, ww, 3.43273939e-07f);
    p = fmaf(p, ww, -3.5233877e-06f);
    p = fmaf(p, ww, -4.39150654e-06f);
    p = fmaf(p, ww, 0.00021858087f);
    p = fmaf(p, ww, -0.00125372503f);
    p = fmaf(p, ww, -0.00417768164f);
    p = fmaf(p, ww, 0.246640727f);
    p = fmaf(p, ww, 1.50140941f);
  } else {
    float ww = sqrtf(w) - 3.0f;
    p = -0.000200214257f;
    p = fmaf(p, ww, 0.000100950558f);
    p = fmaf(p, ww, 0.00134934322f);
    p = fmaf(p, ww, -0.00367342844f);
    p = fmaf(p, ww, 0.00573950773f);
    p = fmaf(p, ww, -0.0076224613f);
    p = fmaf(p, ww, 0.00943887047f);
    p = fmaf(p, ww, 1.00167406f);
    p = fmaf(p, ww, 2.83297682f);
  }
  return 1.41421356f * (p * u);
}

// stage one sample-tile's h/gA/gB columns (owners = lanes with grp==st)
__device__ __forceinline__ void stage_tile(char* buf, int st, int grp, int colL,
    const unsigned int* hp, const unsigned int* gap, const unsigned int* gbp){
  if (grp == st){
    const int rbase = colL * 128;
    const int sw = (colL & 7) << 4;
#pragma unroll
    for (int w = 0; w < 8; ++w){
      int off = rbase + ((w * 16) ^ sw);
      *(uint4v*)(buf + off)        = uint4v{hp[w*4],  hp[w*4+1],  hp[w*4+2],  hp[w*4+3]};
      *(uint4v*)(buf + 2048 + off) = uint4v{gap[w*4], gap[w*4+1], gap[w*4+2], gap[w*4+3]};
      *(uint4v*)(buf + 4096 + off) = uint4v{gbp[w*4], gbp[w*4+1], gbp[w*4+2], gbp[w*4+3]};
    }
  }
}

// MFMA net eval, C[n, sample]. A = Wh^T read from LDS at point of use
// (R7 lesson: never hoist LDS-resident read-only data to long-lived regs).
// B = h/gA/gB sample columns staged in a SINGLE per-wave buffer, written and
// read in the same wave's program order (R6-proven; the R7/R8 double-buffer
// correlated with a 5.5 GB FETCH pathology). n-reduction via shfl_xor(16,32)
// butterfly; lane keeps tile st==grp. No LDS scratch round-trip.
__device__ __forceinline__ void net_eval(
    float y2, float y3,
    const float* __restrict__ sIn,    // [64][4] f32 {w0a,w0b,b0,pad}
    char* sAw,                        // per-wave single buffer [3][16][128B]
    const char* __restrict__ sBb,     // Wh^T bf16 swizzled [96][128B]
    const float* __restrict__ sBW,    // [3][32] (bh, wo) f32 pairs
    int colL, int grp,
    const float* bo_v,
    float& q1o, float& q2o, float& q3o,
    float& s11, float& s21, float& s31,
    float& s12, float& s22, float& s32)
{
  // ---- first layer (f32, per-lane = per-sample), pack bf16 columns ----
  unsigned int hp[32], gap[32], gbp[32];
#pragma unroll
  for (int d = 0; d < 32; ++d){
    float4 iA = ((const float4*)sIn)[2*d];
    float4 iB = ((const float4*)sIn)[2*d+1];
    float preA = fmaf(y2, iA.x, fmaf(y3, iA.y, iA.z));
    float preB = fmaf(y2, iB.x, fmaf(y3, iB.y, iB.z));
    float hA = fast_tanh(preA), hB = fast_tanh(preB);
    float uA = fmaf(-hA, hA, 1.0f), uB = fmaf(-hB, hB, 1.0f);
    hp[d]  = pack2bf(hA, hB);
    gap[d] = pack2bf(uA*iA.x, uB*iB.x);
    gbp[d] = pack2bf(uA*iA.y, uB*iB.y);
  }

  float qraw[3], Araw[3], Braw[3];
#pragma unroll
  for (int hd = 0; hd < 3; ++hd){ qraw[hd]=0.0f; Araw[hd]=0.0f; Braw[hd]=0.0f; }

  const int bsw = (colL & 7) << 4;   // swizzle key (row = colL)

#pragma unroll 1
  for (int st = 0; st < 4; ++st){
    // ---- stage this tile (in-place; same-wave program order makes the
    //      overwrite of the previous tile safe) ----
    stage_tile(sAw, st, grp, colL, hp, gap, gbp);

    // ---- B fragments for this tile (sample columns) ----
    bf16x8 afh[2], afg2[2], afg3[2];
#pragma unroll
    for (int kt = 0; kt < 2; ++kt){
      int off = colL*128 + ((kt*64 + grp*16) ^ bsw);
      afh[kt]  = *(const bf16x8*)(sAw + off);
      afg2[kt] = *(const bf16x8*)(sAw + 2048 + off);
      afg3[kt] = *(const bf16x8*)(sAw + 4096 + off);
    }

#pragma unroll
    for (int hd = 0; hd < 3; ++hd){
      float qp = 0.0f, Ap = 0.0f, Bp = 0.0f;
#pragma unroll
      for (int nt = 0; nt < 2; ++nt){
        // Wh^T fragments from LDS at point of use
        bf16x8 bfr[2];
#pragma unroll
        for (int kt = 0; kt < 2; ++kt){
          int nrow = hd*32 + nt*16 + colL;
          int off = nrow*128 + ((kt*64 + grp*16) ^ bsw);
          bfr[kt] = *(const bf16x8*)(sBb + off);
        }
        int pbase = (hd*32 + nt*16 + grp*4) >> 1;     // (bh,wo) pairs, f32x4 units
        f32x4 v0 = ((const f32x4*)sBW)[pbase];
        f32x4 v1 = ((const f32x4*)sBW)[pbase + 1];
        f32x4 cAT = {0,0,0,0}, cA2 = {0,0,0,0}, cA3 = {0,0,0,0};
#pragma unroll
        for (int kt = 0; kt < 2; ++kt){
          cAT = __builtin_amdgcn_mfma_f32_16x16x32_bf16(bfr[kt], afh[kt],  cAT, 0, 0, 0);
          cA2 = __builtin_amdgcn_mfma_f32_16x16x32_bf16(bfr[kt], afg2[kt], cA2, 0, 0, 0);
          cA3 = __builtin_amdgcn_mfma_f32_16x16x32_bf16(bfr[kt], afg3[kt], cA3, 0, 0, 0);
        }
        float bhv[4] = {v0.x, v0.z, v1.x, v1.z};
        float wov[4] = {v0.y, v0.w, v1.y, v1.w};
#pragma unroll
        for (int r = 0; r < 4; ++r){
          float t  = fast_tanh(cAT[r] + bhv[r]);
          float dt = fmaf(-t, t, 1.0f);
          qp = fmaf(t, wov[r], qp);
          Ap = fmaf(dt * cA2[r], wov[r], Ap);
          Bp = fmaf(dt * cA3[r], wov[r], Bp);
        }
      }
      // full butterfly over the 4 row-groups -> all lanes get the n-sum
      qp += __shfl_xor(qp, 16, 64);  qp += __shfl_xor(qp, 32, 64);
      Ap += __shfl_xor(Ap, 16, 64);  Ap += __shfl_xor(Ap, 32, 64);
      Bp += __shfl_xor(Bp, 16, 64);  Bp += __shfl_xor(Bp, 32, 64);
      // lane keeps its own sample's tile
      bool keep = (st == grp);
      qraw[hd] = keep ? qp : qraw[hd];
      Araw[hd] = keep ? Ap : Araw[hd];
      Braw[hd] = keep ? Bp : Braw[hd];
    }
  }

  const float SIG = 0.03f;
  q1o = __expf(qraw[0] + bo_v[0]);
  q2o = __expf(qraw[1] + bo_v[1]);
  q3o = __expf(qraw[2] + bo_v[2]);
  s11 = SIG * Araw[0]; s21 = SIG * Araw[1]; s31 = SIG * Araw[2];
  s12 = SIG * Braw[0]; s22 = SIG * Braw[1]; s32 = SIG * Braw[2];
}

// NOTE: no min-waves __launch_bounds__ arg — it forces accumulator spills
// ((256,3)->210GB, (256,4)->42GB scratch writes). Natural allocation is clean.
__global__ __launch_bounds__(NB)
void sim_kernel(const float* __restrict__ Y,
  const float* __restrict__ W0,  const float* __restrict__ b0,
  const float* __restrict__ Wh1, const float* __restrict__ bh1,
  const float* __restrict__ Wo1, const float* __restrict__ bo1,
  const float* __restrict__ Wh2, const float* __restrict__ bh2,
  const float* __restrict__ Wo2, const float* __restrict__ bo2,
  const float* __restrict__ Wh3, const float* __restrict__ bh3,
  const float* __restrict__ Wo3, const float* __restrict__ bo3,
  float* __restrict__ out, int n)
{
  __shared__ __align__(16) char  sB[96 * 128];        // Wh^T bf16, swizzled (12 KB)
  __shared__ __align__(16) char  sA[4][3 * 16 * 128]; // per-wave single buffer (24 KB)
  __shared__ __align__(16) float sBW[3 * 32 * 2];     // (bh, wo) pairs
  __shared__ __align__(16) float sIn[64 * 4];

  // ---- init B = Wh^T (bf16, swizzled) ----
  for (int e = threadIdx.x; e < 6144; e += NB){
    int hd = e >> 11, rem = e & 2047, j = rem >> 5, i = rem & 31;
    const float* W = (hd == 0) ? Wh1 : (hd == 1) ? Wh2 : Wh3;
    float v = W[j * 32 + i];
    int nrow = hd * 32 + i;
    int off = (nrow * 128 + j * 2) ^ ((nrow & 7) << 4);
    *(unsigned short*)(sB + off) = (unsigned short)f2bfbits(v);
  }
  if (threadIdx.x < 64){
    int j = threadIdx.x;
    sIn[j*4+0] = W0[j]; sIn[j*4+1] = W0[64+j]; sIn[j*4+2] = b0[j]; sIn[j*4+3] = 0.0f;
  }
  if (threadIdx.x < 96){
    int hd = threadIdx.x >> 5, row = threadIdx.x & 31;
    const float* BH = (hd == 0) ? bh1 : (hd == 1) ? bh2 : bh3;
    const float* WO = (hd == 0) ? Wo1 : (hd == 1) ? Wo2 : Wo3;
    sBW[threadIdx.x * 2 + 0] = BH[row];
    sBW[threadIdx.x * 2 + 1] = WO[row];
  }
  __syncthreads();

  const int wv   = threadIdx.x >> 6;
  const int lane = threadIdx.x & 63;
  const int colL = lane & 15;
  const int grp  = lane >> 4;
  char* sAw = &sA[wv][0];

  float bo_v[3] = {bo1[0], bo2[0], bo3[0]};

  const int gid = blockIdx.x * NB + threadIdx.x;
  const int ii  = (gid < n) ? gid : (n - 1);
  const float valid = (gid < n) ? 1.0f : 0.0f;

  const float2 yv = ((const float2*)Y)[ii];
  const float y2 = yv.x, y3 = yv.y;

  const float GAMMA = 1.2f, DT = 0.005f, SIGMA = 0.03f;
  const float KAPPA = 0.2f, YBAR = 2.0f, RHO = 0.03f, Bc = 1.0f, Cc = 0.1f;

  float q1,q2,q3,s11,s21,s31,s12,s22,s32;
  net_eval(y2, y3, sIn, sAw, sB, sBW, colL, grp, bo_v,
           q1,q2,q3,s11,s21,s31,s12,s22,s32);
  float Y2 = y2, Y3 = y3;
  float loss = 0.0f;

#pragma unroll 1   // t-loop is carry-serial; unrolling only bloats I$
  for (int t = 0; t < PERIOD; ++t){
    // --- noise: threefry rollout, counter = flat index (bit-exact) ---
    uint32_t idx0 = 2u * ((uint32_t)t * (uint32_t)n + (uint32_t)ii);
    uint32_t a0, a1, c0, c1;
    threefry2x32_k42(0u, idx0,      a0, a1);
    threefry2x32_k42(0u, idx0 + 1u, c0, c1);
    float dZ1 = 0.070710678f * normal_from_bits(a0 ^ a1);
    float dZ2 = 0.070710678f * normal_from_bits(c0 ^ c1);

    // --- step math (mirror reference, f32) ---
    float Wt  = q1 + q2 + q3;
    float q1h = q1 / Wt;
    float q2h = q2 / Wt;
    float q3h = 1.0f - q1h - q2h;
    float q1sq = q1 * q1;
    float c   = Bc*q1 - Cc*q1sq + Y2 + Y3;
    float bq  = Bc*q1 - 2.0f*Cc*q1sq;
    float sc1 = fmaf(bq, s11, SIGMA);
    float sc2 = fmaf(bq, s12, SIGMA);
    float sW1 = q1*s11 + q2*s21 + q3*s31;
    float sW2 = q1*s12 + q2*s22 + q3*s32;
    float sJ1 = 6.0f * (sc1/c - sW1/Wt);
    float sJ2 = 6.0f * (sc2/c - sW2/Wt);
    float d11 = s11*s11 + s12*s12;
    float d12 = s11*s21 + s12*s22;
    float d13 = s11*s31 + s12*s32;
    float d22 = s21*s21 + s22*s22;
    float d23 = s21*s31 + s22*s32;
    float d33 = s31*s31 + s32*s32;
    const float oneMG = 1.0f - GAMMA;   // -0.2
    float p1 = GAMMA*(q1h*d11 + q2h*d12 + q3h*d13) - oneMG*(sJ1*s11 + sJ2*s12);
    float p2 = GAMMA*(q1h*d12 + q2h*d22 + q3h*d23) - oneMG*(sJ1*s21 + sJ2*s22);
    float p3 = GAMMA*(q1h*d13 + q2h*d23 + q3h*d33) - oneMG*(sJ1*s31 + sJ2*s32);
    float muY2 = KAPPA * (YBAR - Y2);
    float muY3 = KAPPA * (YBAR - Y3);
    float r = RHO + GAMMA*(bq*(p1 - (Bc - Cc*q1)) - Cc*q1sq*d11 + muY2 + muY3)/c
                  - 1.32f*(sc1*sc1 + sc2*sc2)/(c*c);
    r = r / (1.0f - GAMMA*bq/c);
    float mu1 = r + p1 - (Bc - Cc*q1);
    float mu2 = r + p2 - Y2/q2;
    float mu3 = r + p3 - Y3/q3;
    float q1n = q1 * (1.0f + mu1*DT + s11*dZ1 + s12*dZ2);
    float q2n = q2 * (1.0f + mu2*DT + s21*dZ1 + s22*dZ2);
    float q3n = q3 * (1.0f + mu3*DT + s31*dZ1 + s32*dZ2);
    float Y2n = Y2 + muY2*DT + SIGMA*dZ1;
    float Y3n = Y3 + muY3*DT + SIGMA*dZ2;

    float qt1, qt2, qt3;
    net_eval(Y2n, Y3n, sIn, sAw, sB, sBW, colL, grp, bo_v,
             qt1,qt2,qt3, s11,s21,s31,s12,s22,s32);

    float e1 = q1n - qt1, e2 = q2n - qt2, e3 = q3n - qt3;
    loss += e1*e1 + e2*e2 + e3*e3;

    q1 = q1n; q2 = q2n; q3 = q3n; Y2 = Y2n; Y3 = Y3n;
  }

  loss *= valid * (1.0f / ((float)15000000));   // / (n * PERIOD)

  // --- block reduction -> one atomic per block ---
#pragma unroll
  for (int off = 32; off > 0; off >>= 1)
    loss += __shfl_down(loss, off, 64);
  __shared__ float sred[NB / 64];
  if (lane == 0) sred[wv] = loss;
  __syncthreads();
  if (threadIdx.x == 0){
    float s = 0.0f;
#pragma unroll
    for (int w = 0; w < NB / 64; ++w) s += sred[w];
    atomicAdd(out, s);
  }
}

extern "C" void kernel_launch(void* const* d_in, const int* in_sizes, int n_in,
                              void* d_out, int out_size, void* d_ws, size_t ws_size,
                              hipStream_t stream)
{
  const float* Y   = (const float*)d_in[0];
  const float* W0  = (const float*)d_in[1];
  const float* b0  = (const float*)d_in[2];
  const float* Wh1 = (const float*)d_in[3];
  const float* bh1 = (const float*)d_in[4];
  const float* Wo1 = (const float*)d_in[5];
  const float* bo1 = (const float*)d_in[6];
  const float* Wh2 = (const float*)d_in[7];
  const float* bh2 = (const float*)d_in[8];
  const float* Wo2 = (const float*)d_in[9];
  const float* bo2 = (const float*)d_in[10];
  const float* Wh3 = (const float*)d_in[11];
  const float* bh3 = (const float*)d_in[12];
  const float* Wo3 = (const float*)d_in[13];
  const float* bo3 = (const float*)d_in[14];

  const int n = in_sizes[0] / 2;

  hipMemsetAsync(d_out, 0, sizeof(float), stream);

  const int grid = (n + NB - 1) / NB;
  sim_kernel<<<grid, NB, 0, stream>>>(Y,
      W0, b0, Wh1, bh1, Wo1, bo1, Wh2, bh2, Wo2, bo2, Wh3, bh3, Wo3, bo3,
      (float*)d_out, n);
}

// Round 10
// 5302.836 us; speedup vs baseline: 1.3643x; 1.3643x over previous
//
#include <hip/hip_runtime.h>
#include <hip/hip_bf16.h>
#include <stdint.h>

#define NB 256
#define PERIOD 30

typedef __bf16  bf16x8 __attribute__((ext_vector_type(8)));
typedef float   f32x4  __attribute__((ext_vector_type(4)));
typedef float   f32x2  __attribute__((ext_vector_type(2)));
typedef unsigned int uint4v __attribute__((ext_vector_type(4)));

__device__ __forceinline__ float frcp(float x){ return __builtin_amdgcn_rcpf(x); }

// tanh(x) = 1 - 2/(exp(2x)+1)
__device__ __forceinline__ float fast_tanh(float x){
  float e = __expf(2.0f*x);
  return fmaf(-2.0f, frcp(e + 1.0f), 1.0f);
}

__device__ __forceinline__ unsigned int f2bfbits(float x){
  union { __hip_bfloat16 b; unsigned short u; } v;
  v.b = __float2bfloat16(x);          // RNE, matches XLA convert
  return (unsigned int)v.u;
}
__device__ __forceinline__ unsigned int pack2bf(float lo, float hi){
  return f2bfbits(lo) | (f2bfbits(hi) << 16);
}

// Threefry-2x32, 20 rounds, key = (0, 42)
__device__ __forceinline__ void threefry2x32_k42(uint32_t x0, uint32_t x1,
                                                 uint32_t& o0, uint32_t& o1){
  const uint32_t ks0 = 0u, ks1 = 42u, ks2 = 0u ^ 42u ^ 0x1BD11BDAu;
  x0 += ks0; x1 += ks1;
#define TFR(rot) { x0 += x1; x1 = (x1 << (rot)) | (x1 >> (32 - (rot))); x1 ^= x0; }
  TFR(13) TFR(15) TFR(26) TFR(6)
  x0 += ks1; x1 += ks2 + 1u;
  TFR(17) TFR(29) TFR(16) TFR(24)
  x0 += ks2; x1 += ks0 + 2u;
  TFR(13) TFR(15) TFR(26) TFR(6)
  x0 += ks0; x1 += ks1 + 3u;
  TFR(17) TFR(29) TFR(16) TFR(24)
  x0 += ks1; x1 += ks2 + 4u;
  TFR(13) TFR(15) TFR(26) TFR(6)
  x0 += ks2; x1 += ks0 + 5u;
#undef TFR
  o0 = x0; o1 = x1;
}

// Mirror jax.random.normal f32 (XLA erfinv polynomial)
__device__ __forceinline__ float normal_from_bits(uint32_t bits){
  float f = __uint_as_float((bits >> 9) | 0x3f800000u) - 1.0f;
  const float lo = -0.99999994f;
  float u = fmaf(f, 2.0f, lo);
  u = fmaxf(u, lo);
  float w = -log1pf(-u*u);
  float p;
  if (w < 5.0f){
    float ww = w - 2.5f;
    p = 2.81022636e-08f;
    p = fmaf(p, ww, 3.43273939e-07f);
    p = fmaf(p, ww, -3.5233877e-06f);
    p = fmaf(p, ww, -4.39150654e-06f);
    p = fmaf(p, ww, 0.00021858087f);
    p = fmaf(p, ww, -0.00125372503f);
    p = fmaf(p, ww, -0.00417768164f);
    p = fmaf(p, ww, 0.246640727f);
    p = fmaf(p, ww, 1.50140941f);
  } else {
    float ww = sqrtf(w) - 3.0f;
    p = -0.000200214257f;
    p = fmaf(p, ww, 0.000100950558f);
    p = fmaf(p, ww, 0.00134934322f);
    p = fmaf(p, ww, -0.00367342844f);
    p = fmaf(p, ww, 0.00573950773f);
    p = fmaf(p, ww, -0.0076224613f);
    p = fmaf(p, ww, 0.00943887047f);
    p = fmaf(p, ww, 1.00167406f);
    p = fmaf(p, ww, 2.83297682f);
  }
  return 1.41421356f * (p * u);
}

// Stage one sample-tile's h/gA/gB rows (owners = lanes with grp==st).
// gA/gB recomputed here from the bf16 h (u = 1-h_bf16^2) + w0 from LDS —
// saves 64 long-lived VGPRs vs buffering gap/gbp (the R6 hog).
__device__ __forceinline__ void stage_tile(char* buf, int st, int grp, int colL,
    const unsigned int* hp, const float* __restrict__ sIn){
  if (grp == st){
    const int rbase = colL * 128;
    const int sw = (colL & 7) << 4;
#pragma unroll
    for (int w = 0; w < 8; ++w){
      unsigned int hv[4], ga[4], gb[4];
#pragma unroll
      for (int c = 0; c < 4; ++c){
        int d = w * 4 + c;
        unsigned int hpair = hp[d];
        float hA = __uint_as_float(hpair << 16);          // low bf16 -> f32
        float hB = __uint_as_float(hpair & 0xffff0000u);  // high bf16 -> f32
        f32x2 w0A = *(const f32x2*)(sIn + 8*d);           // {w0a, w0b} j=2d
        f32x2 w0B = *(const f32x2*)(sIn + 8*d + 4);       // j=2d+1
        float uA = fmaf(-hA, hA, 1.0f);
        float uB = fmaf(-hB, hB, 1.0f);
        hv[c] = hpair;
        ga[c] = pack2bf(uA * w0A.x, uB * w0B.x);
        gb[c] = pack2bf(uA * w0A.y, uB * w0B.y);
      }
      int off = rbase + ((w * 16) ^ sw);
      *(uint4v*)(buf + off)        = uint4v{hv[0], hv[1], hv[2], hv[3]};
      *(uint4v*)(buf + 2048 + off) = uint4v{ga[0], ga[1], ga[2], ga[3]};
      *(uint4v*)(buf + 4096 + off) = uint4v{gb[0], gb[1], gb[2], gb[3]};
    }
  }
}

// MFMA net eval, R6-proven orientation: C[sample, n]. A = h/gA/gB sample rows
// (staged per tile, single in-place per-wave buffer, same-wave program order).
// B = Wh^T read from LDS at point of use (R7 lesson: never hoist LDS-resident
// read-only data into long-lived registers). bh/wo pairs from LDS per use.
// Tail: 4-step shfl_xor reduce over 16 col-lanes; scr redistribute (raw q-sum,
// exp applied post-readback: 3 exps/thread instead of 12 exec-masked).
__device__ __forceinline__ void net_eval(
    float y2, float y3,
    const float* __restrict__ sIn,    // [64][4] f32 {w0a,w0b,b0,pad}
    char* sAw,                        // this wave's A buffer: [3][16][128B]
    const char* __restrict__ sBb,     // Wh^T bf16 swizzled [96][128B]
    const float* __restrict__ sBW,    // [96][2] = (bh, wo) per n-row
    float* scr,                       // this wave's [64][12] f32
    int colL, int grp,
    const float* bo_v,
    float& q1o, float& q2o, float& q3o,
    float& s11, float& s21, float& s31,
    float& s12, float& s22, float& s32)
{
  // ---- first layer (f32, per-lane = per-sample): h pairs only ----
  unsigned int hp[32];
#pragma unroll
  for (int d = 0; d < 32; ++d){
    float4 iA = ((const float4*)sIn)[2*d];
    float4 iB = ((const float4*)sIn)[2*d+1];
    float preA = fmaf(y2, iA.x, fmaf(y3, iA.y, iA.z));
    float preB = fmaf(y2, iB.x, fmaf(y3, iB.y, iB.z));
    hp[d] = pack2bf(fast_tanh(preA), fast_tanh(preB));
  }

  const float SIG = 0.03f;
  const int bsw = (colL & 7) << 4;

#pragma unroll 1
  for (int st = 0; st < 4; ++st){
    // stage this tile in-place (same-wave program order -> overwrite safe)
    stage_tile(sAw, st, grp, colL, hp, sIn);

    // A fragments for this tile
    bf16x8 af[3][2];
#pragma unroll
    for (int m = 0; m < 3; ++m)
#pragma unroll
      for (int kt = 0; kt < 2; ++kt){
        int off = m*2048 + colL*128 + ((kt*64 + grp*16) ^ bsw);
        af[m][kt] = *(const bf16x8*)(sAw + off);
      }

#pragma unroll
    for (int hd = 0; hd < 3; ++hd){
      float aq[4] = {0,0,0,0}, aA[4] = {0,0,0,0}, aB[4] = {0,0,0,0};
#pragma unroll
      for (int nt = 0; nt < 2; ++nt){
        int nrow = hd*32 + nt*16 + colL;
        // Wh^T fragments from LDS at point of use
        bf16x8 bfr[2];
#pragma unroll
        for (int kt = 0; kt < 2; ++kt){
          int off = nrow*128 + ((kt*64 + grp*16) ^ bsw);
          bfr[kt] = *(const bf16x8*)(sBb + off);
        }
        f32x2 bw = *(const f32x2*)(sBW + nrow*2);   // (bh, wo) for this lane's n
        f32x4 cAT = {0,0,0,0}, cA2 = {0,0,0,0}, cA3 = {0,0,0,0};
#pragma unroll
        for (int kt = 0; kt < 2; ++kt){
          cAT = __builtin_amdgcn_mfma_f32_16x16x32_bf16(af[0][kt], bfr[kt], cAT, 0, 0, 0);
          cA2 = __builtin_amdgcn_mfma_f32_16x16x32_bf16(af[1][kt], bfr[kt], cA2, 0, 0, 0);
          cA3 = __builtin_amdgcn_mfma_f32_16x16x32_bf16(af[2][kt], bfr[kt], cA3, 0, 0, 0);
        }
#pragma unroll
        for (int r = 0; r < 4; ++r){
          float t  = fast_tanh(cAT[r] + bw.x);
          float dt = fmaf(-t, t, 1.0f);
          aq[r] = fmaf(t, bw.y, aq[r]);
          aA[r] = fmaf(dt * cA2[r], bw.y, aA[r]);
          aB[r] = fmaf(dt * cA3[r], bw.y, aB[r]);
        }
      }
      // reduce across the 16 col-lanes (bits 0-3)
#pragma unroll
      for (int r = 0; r < 4; ++r){
        float q = aq[r], A = aA[r], Bv = aB[r];
#pragma unroll
        for (int d = 1; d < 16; d <<= 1){
          q  += __shfl_xor(q,  d, 64);
          A  += __shfl_xor(A,  d, 64);
          Bv += __shfl_xor(Bv, d, 64);
        }
        if (colL == 0){
          int samp = st*16 + grp*4 + r;
          *(f32x4*)(scr + samp*12 + hd*4) = f32x4{q, SIG*A, SIG*Bv, 0.0f};
        }
      }
    }
  }

  // ---- read back own sample's 9 values; exp applied here (3/thread) ----
  int lane = grp*16 + colL;
  f32x4 h1 = *(const f32x4*)(scr + lane*12 + 0);
  f32x4 h2 = *(const f32x4*)(scr + lane*12 + 4);
  f32x4 h3 = *(const f32x4*)(scr + lane*12 + 8);
  q1o = __expf(h1.x + bo_v[0]); s11 = h1.y; s12 = h1.z;
  q2o = __expf(h2.x + bo_v[1]); s21 = h2.y; s22 = h2.z;
  q3o = __expf(h3.x + bo_v[2]); s31 = h3.y; s32 = h3.z;
}

// NOTE: no min-waves __launch_bounds__ arg — it forces accumulator spills
// ((256,3)->210GB, (256,4)->42GB scratch writes). Natural allocation is clean.
__global__ __launch_bounds__(NB)
void sim_kernel(const float* __restrict__ Y,
  const float* __restrict__ W0,  const float* __restrict__ b0,
  const float* __restrict__ Wh1, const float* __restrict__ bh1,
  const float* __restrict__ Wo1, const float* __restrict__ bo1,
  const float* __restrict__ Wh2, const float* __restrict__ bh2,
  const float* __restrict__ Wo2, const float* __restrict__ bo2,
  const float* __restrict__ Wh3, const float* __restrict__ bh3,
  const float* __restrict__ Wo3, const float* __restrict__ bo3,
  float* __restrict__ out, int n)
{
  __shared__ __align__(16) char  sB[96 * 128];        // Wh^T bf16, swizzled (12 KB)
  __shared__ __align__(16) char  sA[4][3 * 16 * 128]; // per-wave A buffers (24 KB)
  __shared__ __align__(16) float sScr[4][64 * 12];    // per-wave redistribute (12 KB)
  __shared__ __align__(16) float sBW[96 * 2];         // (bh, wo) per n-row
  __shared__ __align__(16) float sIn[64 * 4];

  // ---- init B = Wh^T (bf16, swizzled) ----
  for (int e = threadIdx.x; e < 6144; e += NB){
    int hd = e >> 11, rem = e & 2047, j = rem >> 5, i = rem & 31;
    const float* W = (hd == 0) ? Wh1 : (hd == 1) ? Wh2 : Wh3;
    float v = W[j * 32 + i];
    int nrow = hd * 32 + i;
    int off = (nrow * 128 + j * 2) ^ ((nrow & 7) << 4);
    *(unsigned short*)(sB + off) = (unsigned short)f2bfbits(v);
  }
  if (threadIdx.x < 64){
    int j = threadIdx.x;
    sIn[j*4+0] = W0[j]; sIn[j*4+1] = W0[64+j]; sIn[j*4+2] = b0[j]; sIn[j*4+3] = 0.0f;
  }
  if (threadIdx.x < 96){
    int hd = threadIdx.x >> 5, row = threadIdx.x & 31;
    const float* BH = (hd == 0) ? bh1 : (hd == 1) ? bh2 : bh3;
    const float* WO = (hd == 0) ? Wo1 : (hd == 1) ? Wo2 : Wo3;
    sBW[threadIdx.x * 2 + 0] = BH[row];
    sBW[threadIdx.x * 2 + 1] = WO[row];
  }
  __syncthreads();

  const int wv   = threadIdx.x >> 6;
  const int lane = threadIdx.x & 63;
  const int colL = lane & 15;
  const int grp  = lane >> 4;
  char*  sAw = &sA[wv][0];
  float* scr = &sScr[wv][0];

  float bo_v[3] = {bo1[0], bo2[0], bo3[0]};

  const int gid = blockIdx.x * NB + threadIdx.x;
  const int ii  = (gid < n) ? gid : (n - 1);
  const float valid = (gid < n) ? 1.0f : 0.0f;

  const float2 yv = ((const float2*)Y)[ii];
  const float y2 = yv.x, y3 = yv.y;

  const float GAMMA = 1.2f, DT = 0.005f, SIGMA = 0.03f;
  const float KAPPA = 0.2f, YBAR = 2.0f, RHO = 0.03f, Bc = 1.0f, Cc = 0.1f;

  float q1,q2,q3,s11,s21,s31,s12,s22,s32;
  net_eval(y2, y3, sIn, sAw, sB, sBW, scr, colL, grp, bo_v,
           q1,q2,q3,s11,s21,s31,s12,s22,s32);
  float Y2 = y2, Y3 = y3;
  float loss = 0.0f;

  for (int t = 0; t < PERIOD; ++t){
    // --- noise: threefry rollout, counter = flat index (bit-exact) ---
    uint32_t idx0 = 2u * ((uint32_t)t * (uint32_t)n + (uint32_t)ii);
    uint32_t a0, a1, c0, c1;
    threefry2x32_k42(0u, idx0,      a0, a1);
    threefry2x32_k42(0u, idx0 + 1u, c0, c1);
    float dZ1 = 0.070710678f * normal_from_bits(a0 ^ a1);
    float dZ2 = 0.070710678f * normal_from_bits(c0 ^ c1);

    // --- step math (mirror reference, f32) ---
    float Wt  = q1 + q2 + q3;
    float q1h = q1 / Wt;
    float q2h = q2 / Wt;
    float q3h = 1.0f - q1h - q2h;
    float q1sq = q1 * q1;
    float c   = Bc*q1 - Cc*q1sq + Y2 + Y3;
    float bq  = Bc*q1 - 2.0f*Cc*q1sq;
    float sc1 = fmaf(bq, s11, SIGMA);
    float sc2 = fmaf(bq, s12, SIGMA);
    float sW1 = q1*s11 + q2*s21 + q3*s31;
    float sW2 = q1*s12 + q2*s22 + q3*s32;
    float sJ1 = 6.0f * (sc1/c - sW1/Wt);
    float sJ2 = 6.0f * (sc2/c - sW2/Wt);
    float d11 = s11*s11 + s12*s12;
    float d12 = s11*s21 + s12*s22;
    float d13 = s11*s31 + s12*s32;
    float d22 = s21*s21 + s22*s22;
    float d23 = s21*s31 + s22*s32;
    float d33 = s31*s31 + s32*s32;
    const float oneMG = 1.0f - GAMMA;   // -0.2
    float p1 = GAMMA*(q1h*d11 + q2h*d12 + q3h*d13) - oneMG*(sJ1*s11 + sJ2*s12);
    float p2 = GAMMA*(q1h*d12 + q2h*d22 + q3h*d23) - oneMG*(sJ1*s21 + sJ2*s22);
    float p3 = GAMMA*(q1h*d13 + q2h*d23 + q3h*d33) - oneMG*(sJ1*s31 + sJ2*s32);
    float muY2 = KAPPA * (YBAR - Y2);
    float muY3 = KAPPA * (YBAR - Y3);
    float r = RHO + GAMMA*(bq*(p1 - (Bc - Cc*q1)) - Cc*q1sq*d11 + muY2 + muY3)/c
                  - 1.32f*(sc1*sc1 + sc2*sc2)/(c*c);
    r = r / (1.0f - GAMMA*bq/c);
    float mu1 = r + p1 - (Bc - Cc*q1);
    float mu2 = r + p2 - Y2/q2;
    float mu3 = r + p3 - Y3/q3;
    float q1n = q1 * (1.0f + mu1*DT + s11*dZ1 + s12*dZ2);
    float q2n = q2 * (1.0f + mu2*DT + s21*dZ1 + s22*dZ2);
    float q3n = q3 * (1.0f + mu3*DT + s31*dZ1 + s32*dZ2);
    float Y2n = Y2 + muY2*DT + SIGMA*dZ1;
    float Y3n = Y3 + muY3*DT + SIGMA*dZ2;

    float qt1, qt2, qt3;
    net_eval(Y2n, Y3n, sIn, sAw, sB, sBW, scr, colL, grp, bo_v,
             qt1,qt2,qt3, s11,s21,s31,s12,s22,s32);

    float e1 = q1n - qt1, e2 = q2n - qt2, e3 = q3n - qt3;
    loss += e1*e1 + e2*e2 + e3*e3;

    q1 = q1n; q2 = q2n; q3 = q3n; Y2 = Y2n; Y3 = Y3n;
  }

  loss *= valid * (1.0f / ((float)15000000));   // / (n * PERIOD)

  // --- block reduction -> one atomic per block ---
#pragma unroll
  for (int off = 32; off > 0; off >>= 1)
    loss += __shfl_down(loss, off, 64);
  __shared__ float sred[NB / 64];
  if (lane == 0) sred[wv] = loss;
  __syncthreads();
  if (threadIdx.x == 0){
    float s = 0.0f;
#pragma unroll
    for (int w = 0; w < NB / 64; ++w) s += sred[w];
    atomicAdd(out, s);
  }
}

extern "C" void kernel_launch(void* const* d_in, const int* in_sizes, int n_in,
                              void* d_out, int out_size, void* d_ws, size_t ws_size,
                              hipStream_t stream)
{
  const float* Y   = (const float*)d_in[0];
  const float* W0  = (const float*)d_in[1];
  const float* b0  = (const float*)d_in[2];
  const float* Wh1 = (const float*)d_in[3];
  const float* bh1 = (const float*)d_in[4];
  const float* Wo1 = (const float*)d_in[5];
  const float* bo1 = (const float*)d_in[6];
  const float* Wh2 = (const float*)d_in[7];
  const float* bh2 = (const float*)d_in[8];
  const float* Wo2 = (const float*)d_in[9];
  const float* bo2 = (const float*)d_in[10];
  const float* Wh3 = (const float*)d_in[11];
  const float* bh3 = (const float*)d_in[12];
  const float* Wo3 = (const float*)d_in[13];
  const float* bo3 = (const float*)d_in[14];

  const int n = in_sizes[0] / 2;

  hipMemsetAsync(d_out, 0, sizeof(float), stream);

  const int grid = (n + NB - 1) / NB;
  sim_kernel<<<grid, NB, 0, stream>>>(Y,
      W0, b0, Wh1, bh1, Wo1, bo1, Wh2, bh2, Wo2, bo2, Wh3, bh3, Wo3, bo3,
      (float*)d_out, n);
}

// Round 12
// 3697.527 us; speedup vs baseline: 1.9566x; 1.4342x over previous
//
#include <hip/hip_runtime.h>
#include <hip/hip_bf16.h>
#include <stdint.h>

#define NB 256
#define PERIOD 30

typedef __bf16  bf16x8 __attribute__((ext_vector_type(8)));
typedef float   f32x4  __attribute__((ext_vector_type(4)));
typedef unsigned int uint4v __attribute__((ext_vector_type(4)));

__device__ __forceinline__ float frcp(float x){ return __builtin_amdgcn_rcpf(x); }

// tanh(x) = 1 - 2/(exp(2x)+1)
__device__ __forceinline__ float fast_tanh(float x){
  float e = __expf(2.0f*x);
  return fmaf(-2.0f, frcp(e + 1.0f), 1.0f);
}

__device__ __forceinline__ unsigned int f2bfbits(float x){
  union { __hip_bfloat16 b; unsigned short u; } v;
  v.b = __float2bfloat16(x);          // RNE, matches XLA convert
  return (unsigned int)v.u;
}
__device__ __forceinline__ unsigned int pack2bf(float lo, float hi){
  return f2bfbits(lo) | (f2bfbits(hi) << 16);
}

// 16-lane row-sum on the VALU pipe (v_add_f32_dpp), zero DS-pipe ops.
// dpp_ctrl must be an immediate -> template parameter.
template <int CTRL>
__device__ __forceinline__ float dpp_add_step(float x){
  int y = __builtin_amdgcn_update_dpp(0, __float_as_int(x), CTRL, 0xf, 0xf, true);
  return x + __int_as_float(y);
}
__device__ __forceinline__ float row16_sum(float x){
  x = dpp_add_step<0xB1>(x);    // quad_perm [1,0,3,2]  (xor 1)
  x = dpp_add_step<0x4E>(x);    // quad_perm [2,3,0,1]  (xor 2)
  x = dpp_add_step<0x124>(x);   // row_ror:4
  x = dpp_add_step<0x128>(x);   // row_ror:8
  return x;                     // all 16 row-lanes hold the row sum
}

// Threefry-2x32, 20 rounds, key = (0, 42)
__device__ __forceinline__ void threefry2x32_k42(uint32_t x0, uint32_t x1,
                                                 uint32_t& o0, uint32_t& o1){
  const uint32_t ks0 = 0u, ks1 = 42u, ks2 = 0u ^ 42u ^ 0x1BD11BDAu;
  x0 += ks0; x1 += ks1;
#define TFR(rot) { x0 += x1; x1 = (x1 << (rot)) | (x1 >> (32 - (rot))); x1 ^= x0; }
  TFR(13) TFR(15) TFR(26) TFR(6)
  x0 += ks1; x1 += ks2 + 1u;
  TFR(17) TFR(29) TFR(16) TFR(24)
  x0 += ks2; x1 += ks0 + 2u;
  TFR(13) TFR(15) TFR(26) TFR(6)
  x0 += ks0; x1 += ks1 + 3u;
  TFR(17) TFR(29) TFR(16) TFR(24)
  x0 += ks1; x1 += ks2 + 4u;
  TFR(13) TFR(15) TFR(26) TFR(6)
  x0 += ks2; x1 += ks0 + 5u;
#undef TFR
  o0 = x0; o1 = x1;
}

// Mirror jax.random.normal f32 (XLA erfinv polynomial)
__device__ __forceinline__ float normal_from_bits(uint32_t bits){
  float f = __uint_as_float((bits >> 9) | 0x3f800000u) - 1.0f;
  const float lo = -0.99999994f;
  float u = fmaf(f, 2.0f, lo);
  u = fmaxf(u, lo);
  float w = -log1pf(-u*u);
  float p;
  if (w < 5.0f){
    float ww = w - 2.5f;
    p = 2.81022636e-08f;
    p = fmaf(p, ww, 3.43273939e-07f);
    p = fmaf(p, ww, -3.5233877e-06f);
    p = fmaf(p, ww, -4.39150654e-06f);
    p = fmaf(p, ww, 0.00021858087f);
    p = fmaf(p, ww, -0.00125372503f);
    p = fmaf(p, ww, -0.00417768164f);
    p = fmaf(p, ww, 0.246640727f);
    p = fmaf(p, ww, 1.50140941f);
  } else {
    float ww = sqrtf(w) - 3.0f;
    p = -0.000200214257f;
    p = fmaf(p, ww, 0.000100950558f);
    p = fmaf(p, ww, 0.00134934322f);
    p = fmaf(p, ww, -0.00367342844f);
    p = fmaf(p, ww, 0.00573950773f);
    p = fmaf(p, ww, -0.0076224613f);
    p = fmaf(p, ww, 0.00943887047f);
    p = fmaf(p, ww, 1.00167406f);
    p = fmaf(p, ww, 2.83297682f);
  }
  return 1.41421356f * (p * u);
}

// stage one sample-tile's h/gA/gB rows (owners = lanes with grp==st);
// packs come straight from registers (no DS reads here).
__device__ __forceinline__ void stage_tile(char* buf, int st, int grp, int colL,
    const unsigned int* hp, const unsigned int* gap, const unsigned int* gbp){
  if (grp == st){
    const int rbase = colL * 128;
    const int sw = (colL & 7) << 4;
#pragma unroll
    for (int w = 0; w < 8; ++w){
      int off = rbase + ((w * 16) ^ sw);
      *(uint4v*)(buf + off)        = uint4v{hp[w*4],  hp[w*4+1],  hp[w*4+2],  hp[w*4+3]};
      *(uint4v*)(buf + 2048 + off) = uint4v{gap[w*4], gap[w*4+1], gap[w*4+2], gap[w*4+3]};
      *(uint4v*)(buf + 4096 + off) = uint4v{gbp[w*4], gbp[w*4+1], gbp[w*4+2], gbp[w*4+3]};
    }
  }
}

// MFMA net eval, R6-proven orientation: C[sample, n]. A = h/gA/gB sample rows
// (single in-place per-wave buffer, same-wave program order). B = Wh^T from
// LDS at point of use (R7 lesson: never hoist LDS fragments to long-lived
// regs). Reduce over the 16 n-lanes via DPP on the VALU pipe (replaces 576
// ds_swizzle shuffles/eval). scr redistribute; exp post-readback.
__device__ __forceinline__ void net_eval(
    float y2, float y3,
    const float* __restrict__ sIn,    // [64][4] f32 {w0a,w0b,b0,pad}
    char* sAw,                        // this wave's A buffer: [3][16][128B]
    const char* __restrict__ sBb,     // Wh^T bf16 swizzled [96][128B]
    float* scr,                       // this wave's [64][12] f32
    int colL, int grp,
    const float (&bh_v)[3][2], const float (&wo_v)[3][2], const float* bo_v,
    float& q1o, float& q2o, float& q3o,
    float& s11, float& s21, float& s31,
    float& s12, float& s22, float& s32)
{
  // ---- first layer (f32, per-lane = per-sample), pack bf16 rows ----
  unsigned int hp[32], gap[32], gbp[32];
#pragma unroll
  for (int d = 0; d < 32; ++d){
    float4 iA = ((const float4*)sIn)[2*d];
    float4 iB = ((const float4*)sIn)[2*d+1];
    float preA = fmaf(y2, iA.x, fmaf(y3, iA.y, iA.z));
    float preB = fmaf(y2, iB.x, fmaf(y3, iB.y, iB.z));
    float hA = fast_tanh(preA), hB = fast_tanh(preB);
    float uA = fmaf(-hA, hA, 1.0f), uB = fmaf(-hB, hB, 1.0f);
    hp[d]  = pack2bf(hA, hB);
    gap[d] = pack2bf(uA*iA.x, uB*iB.x);
    gbp[d] = pack2bf(uA*iA.y, uB*iB.y);
  }

  const float SIG = 0.03f;
  const int bsw = (colL & 7) << 4;

#pragma unroll 1
  for (int st = 0; st < 4; ++st){
    // stage this tile in-place (same-wave program order -> overwrite safe)
    stage_tile(sAw, st, grp, colL, hp, gap, gbp);

    // A fragments for this tile
    bf16x8 af[3][2];
#pragma unroll
    for (int m = 0; m < 3; ++m)
#pragma unroll
      for (int kt = 0; kt < 2; ++kt){
        int off = m*2048 + colL*128 + ((kt*64 + grp*16) ^ bsw);
        af[m][kt] = *(const bf16x8*)(sAw + off);
      }

#pragma unroll
    for (int hd = 0; hd < 3; ++hd){
      float aq[4] = {0,0,0,0}, aA[4] = {0,0,0,0}, aB[4] = {0,0,0,0};
#pragma unroll
      for (int nt = 0; nt < 2; ++nt){
        // Wh^T fragments from LDS at point of use
        bf16x8 bfr[2];
#pragma unroll
        for (int kt = 0; kt < 2; ++kt){
          int nrow = hd*32 + nt*16 + colL;
          int off = nrow*128 + ((kt*64 + grp*16) ^ bsw);
          bfr[kt] = *(const bf16x8*)(sBb + off);
        }
        f32x4 cAT = {0,0,0,0}, cA2 = {0,0,0,0}, cA3 = {0,0,0,0};
#pragma unroll
        for (int kt = 0; kt < 2; ++kt){
          cAT = __builtin_amdgcn_mfma_f32_16x16x32_bf16(af[0][kt], bfr[kt], cAT, 0, 0, 0);
          cA2 = __builtin_amdgcn_mfma_f32_16x16x32_bf16(af[1][kt], bfr[kt], cA2, 0, 0, 0);
          cA3 = __builtin_amdgcn_mfma_f32_16x16x32_bf16(af[2][kt], bfr[kt], cA3, 0, 0, 0);
        }
        float bh = bh_v[hd][nt], wo = wo_v[hd][nt];
#pragma unroll
        for (int r = 0; r < 4; ++r){
          float t  = fast_tanh(cAT[r] + bh);
          float dt = fmaf(-t, t, 1.0f);
          aq[r] = fmaf(t, wo, aq[r]);
          aA[r] = fmaf(dt * cA2[r], wo, aA[r]);
          aB[r] = fmaf(dt * cA3[r], wo, aB[r]);
        }
      }
      // reduce across the 16 col-lanes on the VALU pipe (DPP)
#pragma unroll
      for (int r = 0; r < 4; ++r){
        float q  = row16_sum(aq[r]);
        float A  = row16_sum(aA[r]);
        float Bv = row16_sum(aB[r]);
        if (colL == 0){
          int samp = st*16 + grp*4 + r;
          *(f32x4*)(scr + samp*12 + hd*4) = f32x4{q, SIG*A, SIG*Bv, 0.0f};
        }
      }
    }
  }

  // ---- read back own sample's 9 values; exp applied here (3/thread) ----
  int lane = grp*16 + colL;
  f32x4 h1 = *(const f32x4*)(scr + lane*12 + 0);
  f32x4 h2 = *(const f32x4*)(scr + lane*12 + 4);
  f32x4 h3 = *(const f32x4*)(scr + lane*12 + 8);
  q1o = __expf(h1.x + bo_v[0]); s11 = h1.y; s12 = h1.z;
  q2o = __expf(h2.x + bo_v[1]); s21 = h2.y; s22 = h2.z;
  q3o = __expf(h3.x + bo_v[2]); s31 = h3.y; s32 = h3.z;
}

// NOTE: no min-waves __launch_bounds__ arg — it forces accumulator spills
// ((256,3)->210GB, (256,4)->42GB scratch writes). Natural allocation is clean.
__global__ __launch_bounds__(NB)
void sim_kernel(const float* __restrict__ Y,
  const float* __restrict__ W0,  const float* __restrict__ b0,
  const float* __restrict__ Wh1, const float* __restrict__ bh1,
  const float* __restrict__ Wo1, const float* __restrict__ bo1,
  const float* __restrict__ Wh2, const float* __restrict__ bh2,
  const float* __restrict__ Wo2, const float* __restrict__ bo2,
  const float* __restrict__ Wh3, const float* __restrict__ bh3,
  const float* __restrict__ Wo3, const float* __restrict__ bo3,
  float* __restrict__ out, int n)
{
  __shared__ __align__(16) char  sB[96 * 128];        // Wh^T bf16, swizzled (12 KB)
  __shared__ __align__(16) char  sA[4][3 * 16 * 128]; // per-wave A buffers (24 KB)
  __shared__ __align__(16) float sScr[4][64 * 12];    // per-wave redistribute (12 KB)
  __shared__ __align__(16) float sIn[64 * 4];

  // ---- init B = Wh^T (bf16, swizzled) ----
  for (int e = threadIdx.x; e < 6144; e += NB){
    int hd = e >> 11, rem = e & 2047, j = rem >> 5, i = rem & 31;
    const float* W = (hd == 0) ? Wh1 : (hd == 1) ? Wh2 : Wh3;
    float v = W[j * 32 + i];
    int nrow = hd * 32 + i;
    int off = (nrow * 128 + j * 2) ^ ((nrow & 7) << 4);
    *(unsigned short*)(sB + off) = (unsigned short)f2bfbits(v);
  }
  if (threadIdx.x < 64){
    int j = threadIdx.x;
    sIn[j*4+0] = W0[j]; sIn[j*4+1] = W0[64+j]; sIn[j*4+2] = b0[j]; sIn[j*4+3] = 0.0f;
  }
  __syncthreads();

  const int wv   = threadIdx.x >> 6;
  const int lane = threadIdx.x & 63;
  const int colL = lane & 15;
  const int grp  = lane >> 4;
  char*  sAw = &sA[wv][0];
  float* scr = &sScr[wv][0];

  // per-lane second-layer constants (scalars in regs — R6-proven safe)
  float bh_v[3][2], wo_v[3][2], bo_v[3];
  {
    const float* BH[3] = {bh1, bh2, bh3};
    const float* WOp[3] = {Wo1, Wo2, Wo3};
#pragma unroll
    for (int hd = 0; hd < 3; ++hd)
#pragma unroll
      for (int nt = 0; nt < 2; ++nt){
        bh_v[hd][nt] = BH[hd][nt*16 + colL];
        wo_v[hd][nt] = WOp[hd][nt*16 + colL];
      }
    bo_v[0] = bo1[0]; bo_v[1] = bo2[0]; bo_v[2] = bo3[0];
  }

  const int gid = blockIdx.x * NB + threadIdx.x;
  const int ii  = (gid < n) ? gid : (n - 1);
  const float valid = (gid < n) ? 1.0f : 0.0f;

  const float2 yv = ((const float2*)Y)[ii];
  const float y2 = yv.x, y3 = yv.y;

  const float GAMMA = 1.2f, DT = 0.005f, SIGMA = 0.03f;
  const float KAPPA = 0.2f, YBAR = 2.0f, RHO = 0.03f, Bc = 1.0f, Cc = 0.1f;

  float q1,q2,q3,s11,s21,s31,s12,s22,s32;
  net_eval(y2, y3, sIn, sAw, sB, scr, colL, grp, bh_v, wo_v, bo_v,
           q1,q2,q3,s11,s21,s31,s12,s22,s32);
  float Y2 = y2, Y3 = y3;
  float loss = 0.0f;

  for (int t = 0; t < PERIOD; ++t){
    // --- noise: threefry rollout, counter = flat index (bit-exact) ---
    uint32_t idx0 = 2u * ((uint32_t)t * (uint32_t)n + (uint32_t)ii);
    uint32_t a0, a1, c0, c1;
    threefry2x32_k42(0u, idx0,      a0, a1);
    threefry2x32_k42(0u, idx0 + 1u, c0, c1);
    float dZ1 = 0.070710678f * normal_from_bits(a0 ^ a1);
    float dZ2 = 0.070710678f * normal_from_bits(c0 ^ c1);

    // --- step math (mirror reference, f32) ---
    float Wt  = q1 + q2 + q3;
    float q1h = q1 / Wt;
    float q2h = q2 / Wt;
    float q3h = 1.0f - q1h - q2h;
    float q1sq = q1 * q1;
    float c   = Bc*q1 - Cc*q1sq + Y2 + Y3;
    float bq  = Bc*q1 - 2.0f*Cc*q1sq;
    float sc1 = fmaf(bq, s11, SIGMA);
    float sc2 = fmaf(bq, s12, SIGMA);
    float sW1 = q1*s11 + q2*s21 + q3*s31;
    float sW2 = q1*s12 + q2*s22 + q3*s32;
    float sJ1 = 6.0f * (sc1/c - sW1/Wt);
    float sJ2 = 6.0f * (sc2/c - sW2/Wt);
    float d11 = s11*s11 + s12*s12;
    float d12 = s11*s21 + s12*s22;
    float d13 = s11*s31 + s12*s32;
    float d22 = s21*s21 + s22*s22;
    float d23 = s21*s31 + s22*s32;
    float d33 = s31*s31 + s32*s32;
    const float oneMG = 1.0f - GAMMA;   // -0.2
    float p1 = GAMMA*(q1h*d11 + q2h*d12 + q3h*d13) - oneMG*(sJ1*s11 + sJ2*s12);
    float p2 = GAMMA*(q1h*d12 + q2h*d22 + q3h*d23) - oneMG*(sJ1*s21 + sJ2*s22);
    float p3 = GAMMA*(q1h*d13 + q2h*d23 + q3h*d33) - oneMG*(sJ1*s31 + sJ2*s32);
    float muY2 = KAPPA * (YBAR - Y2);
    float muY3 = KAPPA * (YBAR - Y3);
    float r = RHO + GAMMA*(bq*(p1 - (Bc - Cc*q1)) - Cc*q1sq*d11 + muY2 + muY3)/c
                  - 1.32f*(sc1*sc1 + sc2*sc2)/(c*c);
    r = r / (1.0f - GAMMA*bq/c);
    float mu1 = r + p1 - (Bc - Cc*q1);
    float mu2 = r + p2 - Y2/q2;
    float mu3 = r + p3 - Y3/q3;
    float q1n = q1 * (1.0f + mu1*DT + s11*dZ1 + s12*dZ2);
    float q2n = q2 * (1.0f + mu2*DT + s21*dZ1 + s22*dZ2);
    float q3n = q3 * (1.0f + mu3*DT + s31*dZ1 + s32*dZ2);
    float Y2n = Y2 + muY2*DT + SIGMA*dZ1;
    float Y3n = Y3 + muY3*DT + SIGMA*dZ2;

    float qt1, qt2, qt3;
    net_eval(Y2n, Y3n, sIn, sAw, sB, scr, colL, grp, bh_v, wo_v, bo_v,
             qt1,qt2,qt3, s11,s21,s31,s12,s22,s32);

    float e1 = q1n - qt1, e2 = q2n - qt2, e3 = q3n - qt3;
    loss += e1*e1 + e2*e2 + e3*e3;

    q1 = q1n; q2 = q2n; q3 = q3n; Y2 = Y2n; Y3 = Y3n;
  }

  loss *= valid * (1.0f / ((float)15000000));   // / (n * PERIOD)

  // --- block reduction -> one atomic per block ---
#pragma unroll
  for (int off = 32; off > 0; off >>= 1)
    loss += __shfl_down(loss, off, 64);
  __shared__ float sred[NB / 64];
  if (lane == 0) sred[wv] = loss;
  __syncthreads();
  if (threadIdx.x == 0){
    float s = 0.0f;
#pragma unroll
    for (int w = 0; w < NB / 64; ++w) s += sred[w];
    atomicAdd(out, s);
  }
}

extern "C" void kernel_launch(void* const* d_in, const int* in_sizes, int n_in,
                              void* d_out, int out_size, void* d_ws, size_t ws_size,
                              hipStream_t stream)
{
  const float* Y   = (const float*)d_in[0];
  const float* W0  = (const float*)d_in[1];
  const float* b0  = (const float*)d_in[2];
  const float* Wh1 = (const float*)d_in[3];
  const float* bh1 = (const float*)d_in[4];
  const float* Wo1 = (const float*)d_in[5];
  const float* bo1 = (const float*)d_in[6];
  const float* Wh2 = (const float*)d_in[7];
  const float* bh2 = (const float*)d_in[8];
  const float* Wo2 = (const float*)d_in[9];
  const float* bo2 = (const float*)d_in[10];
  const float* Wh3 = (const float*)d_in[11];
  const float* bh3 = (const float*)d_in[12];
  const float* Wo3 = (const float*)d_in[13];
  const float* bo3 = (const float*)d_in[14];

  const int n = in_sizes[0] / 2;

  (void)hipMemsetAsync(d_out, 0, sizeof(float), stream);

  const int grid = (n + NB - 1) / NB;
  sim_kernel<<<grid, NB, 0, stream>>>(Y,
      W0, b0, Wh1, bh1, Wo1, bo1, Wh2, bh2, Wo2, bo2, Wh3, bh3, Wo3, bo3,
      (float*)d_out, n);
}

// Round 13
// 2700.413 us; speedup vs baseline: 2.6791x; 1.3692x over previous
//
#include <hip/hip_runtime.h>
#include <hip/hip_bf16.h>
#include <stdint.h>

#define NB 256
#define PERIOD 30

typedef __bf16  bf16x8 __attribute__((ext_vector_type(8)));
typedef float   f32x4  __attribute__((ext_vector_type(4)));
typedef unsigned int uint4v __attribute__((ext_vector_type(4)));

__device__ __forceinline__ float frcp(float x){ return __builtin_amdgcn_rcpf(x); }

// tanh(x) = 1 - 2/(exp(2x)+1)
__device__ __forceinline__ float fast_tanh(float x){
  float e = __expf(2.0f*x);
  return fmaf(-2.0f, frcp(e + 1.0f), 1.0f);
}

__device__ __forceinline__ unsigned int f2bfbits(float x){
  union { __hip_bfloat16 b; unsigned short u; } v;
  v.b = __float2bfloat16(x);          // RNE, matches XLA convert
  return (unsigned int)v.u;
}
__device__ __forceinline__ unsigned int pack2bf(float lo, float hi){
  return f2bfbits(lo) | (f2bfbits(hi) << 16);
}

// 16-lane row-sum on the VALU pipe (v_add_f32_dpp); dpp_ctrl must be an
// immediate -> template parameter.
template <int CTRL>
__device__ __forceinline__ float dpp_add_step(float x){
  int y = __builtin_amdgcn_update_dpp(0, __float_as_int(x), CTRL, 0xf, 0xf, true);
  return x + __int_as_float(y);
}
__device__ __forceinline__ float row16_sum(float x){
  x = dpp_add_step<0xB1>(x);    // quad_perm [1,0,3,2]  (xor 1)
  x = dpp_add_step<0x4E>(x);    // quad_perm [2,3,0,1]  (xor 2)
  x = dpp_add_step<0x124>(x);   // row_ror:4
  x = dpp_add_step<0x128>(x);   // row_ror:8
  return x;                     // all 16 row-lanes hold the row sum
}

// Threefry-2x32, 20 rounds, key = (0, 42)
__device__ __forceinline__ void threefry2x32_k42(uint32_t x0, uint32_t x1,
                                                 uint32_t& o0, uint32_t& o1){
  const uint32_t ks0 = 0u, ks1 = 42u, ks2 = 0u ^ 42u ^ 0x1BD11BDAu;
  x0 += ks0; x1 += ks1;
#define TFR(rot) { x0 += x1; x1 = (x1 << (rot)) | (x1 >> (32 - (rot))); x1 ^= x0; }
  TFR(13) TFR(15) TFR(26) TFR(6)
  x0 += ks1; x1 += ks2 + 1u;
  TFR(17) TFR(29) TFR(16) TFR(24)
  x0 += ks2; x1 += ks0 + 2u;
  TFR(13) TFR(15) TFR(26) TFR(6)
  x0 += ks0; x1 += ks1 + 3u;
  TFR(17) TFR(29) TFR(16) TFR(24)
  x0 += ks1; x1 += ks2 + 4u;
  TFR(13) TFR(15) TFR(26) TFR(6)
  x0 += ks2; x1 += ks0 + 5u;
#undef TFR
  o0 = x0; o1 = x1;
}

// Mirror jax.random.normal f32 (XLA erfinv polynomial)
__device__ __forceinline__ float normal_from_bits(uint32_t bits){
  float f = __uint_as_float((bits >> 9) | 0x3f800000u) - 1.0f;
  const float lo = -0.99999994f;
  float u = fmaf(f, 2.0f, lo);
  u = fmaxf(u, lo);
  float w = -log1pf(-u*u);
  float p;
  if (w < 5.0f){
    float ww = w - 2.5f;
    p = 2.81022636e-08f;
    p = fmaf(p, ww, 3.43273939e-07f);
    p = fmaf(p, ww, -3.5233877e-06f);
    p = fmaf(p, ww, -4.39150654e-06f);
    p = fmaf(p, ww, 0.00021858087f);
    p = fmaf(p, ww, -0.00125372503f);
    p = fmaf(p, ww, -0.00417768164f);
    p = fmaf(p, ww, 0.246640727f);
    p = fmaf(p, ww, 1.50140941f);
  } else {
    float ww = sqrtf(w) - 3.0f;
    p = -0.000200214257f;
    p = fmaf(p, ww, 0.000100950558f);
    p = fmaf(p, ww, 0.00134934322f);
    p = fmaf(p, ww, -0.00367342844f);
    p = fmaf(p, ww, 0.00573950773f);
    p = fmaf(p, ww, -0.0076224613f);
    p = fmaf(p, ww, 0.00943887047f);
    p = fmaf(p, ww, 1.00167406f);
    p = fmaf(p, ww, 2.83297682f);
  }
  return 1.41421356f * (p * u);
}

// stage one sample-tile's h/u rows (owners = lanes with grp==st)
__device__ __forceinline__ void stage_tile(char* buf, int st, int grp, int colL,
    const unsigned int* hp, const unsigned int* up){
  if (grp == st){
    const int rbase = colL * 128;
    const int sw = (colL & 7) << 4;
#pragma unroll
    for (int w = 0; w < 8; ++w){
      int off = rbase + ((w * 16) ^ sw);
      *(uint4v*)(buf + off)        = uint4v{hp[w*4], hp[w*4+1], hp[w*4+2], hp[w*4+3]};
      *(uint4v*)(buf + 2048 + off) = uint4v{up[w*4], up[w*4+1], up[w*4+2], up[w*4+3]};
    }
  }
}

// MFMA net eval with folded JVP weights: staged A = {h, u=1-h^2} only;
// B = {Wh^T, (diag(w0a)Wh)^T, (diag(w0b)Wh)^T} per head from LDS at point of
// use (R7 lesson: never hoist LDS fragments to long-lived regs). Reduce over
// the 16 n-lanes via DPP (VALU pipe); redistribute via one ds_bpermute pull
// per value (replaces the scr LDS round-trip). W0/b0 read from global with
// constant offsets -> scalar s_load on the K$ path (wave-uniform).
__device__ __forceinline__ void net_eval(
    float y2, float y3,
    const float* __restrict__ W0, const float* __restrict__ b0,
    char* sAw,                        // this wave's A buffer: [2][16][128B]
    const char* __restrict__ sBb,     // B matrices [3hd][3mat][32n][128B]
    int colL, int grp,
    const float (&bh_v)[3][2], const float (&wo_v)[3][2], const float* bo_v,
    float& q1o, float& q2o, float& q3o,
    float& s11, float& s21, float& s31,
    float& s12, float& s22, float& s32)
{
  // ---- first layer (f32, per-lane = per-sample): h and u packs ----
  unsigned int hp[32], up[32];
#pragma unroll
  for (int d = 0; d < 32; ++d){
    float w0aA = W0[2*d],      w0aB = W0[2*d + 1];
    float w0bA = W0[64 + 2*d], w0bB = W0[65 + 2*d];
    float b0A  = b0[2*d],      b0B  = b0[2*d + 1];
    float preA = fmaf(y2, w0aA, fmaf(y3, w0bA, b0A));
    float preB = fmaf(y2, w0aB, fmaf(y3, w0bB, b0B));
    float hA = fast_tanh(preA), hB = fast_tanh(preB);
    hp[d] = pack2bf(hA, hB);
    up[d] = pack2bf(fmaf(-hA, hA, 1.0f), fmaf(-hB, hB, 1.0f));
  }

  float qraw[3] = {0,0,0}, Araw[3] = {0,0,0}, Braw[3] = {0,0,0};
  const int bsw  = (colL & 7) << 4;
  const int srcL = ((colL >> 2) << 4) | colL;   // bpermute source lane

#pragma unroll 1
  for (int st = 0; st < 4; ++st){
    // stage this tile in-place (same-wave program order -> overwrite safe)
    stage_tile(sAw, st, grp, colL, hp, up);

    // A fragments for this tile
    bf16x8 afh[2], afu[2];
#pragma unroll
    for (int kt = 0; kt < 2; ++kt){
      int off = colL*128 + ((kt*64 + grp*16) ^ bsw);
      afh[kt] = *(const bf16x8*)(sAw + off);
      afu[kt] = *(const bf16x8*)(sAw + 2048 + off);
    }

#pragma unroll
    for (int hd = 0; hd < 3; ++hd){
      float aq[4] = {0,0,0,0}, aA[4] = {0,0,0,0}, aB[4] = {0,0,0,0};
#pragma unroll
      for (int nt = 0; nt < 2; ++nt){
        // B fragments (3 matrices) from LDS at point of use
        bf16x8 bW[2], bA[2], bB[2];
#pragma unroll
        for (int kt = 0; kt < 2; ++kt){
          int rbase2 = (hd*96 + nt*16 + colL) * 128;
          int ko = ((kt*64 + grp*16) ^ bsw);
          bW[kt] = *(const bf16x8*)(sBb + rbase2 + ko);
          bA[kt] = *(const bf16x8*)(sBb + rbase2 + 4096 + ko);
          bB[kt] = *(const bf16x8*)(sBb + rbase2 + 8192 + ko);
        }
        f32x4 cAT = {0,0,0,0}, cA2 = {0,0,0,0}, cA3 = {0,0,0,0};
#pragma unroll
        for (int kt = 0; kt < 2; ++kt){
          cAT = __builtin_amdgcn_mfma_f32_16x16x32_bf16(afh[kt], bW[kt], cAT, 0, 0, 0);
          cA2 = __builtin_amdgcn_mfma_f32_16x16x32_bf16(afu[kt], bA[kt], cA2, 0, 0, 0);
          cA3 = __builtin_amdgcn_mfma_f32_16x16x32_bf16(afu[kt], bB[kt], cA3, 0, 0, 0);
        }
        float bh = bh_v[hd][nt], wo = wo_v[hd][nt];
#pragma unroll
        for (int r = 0; r < 4; ++r){
          float t  = fast_tanh(cAT[r] + bh);
          float dt = fmaf(-t, t, 1.0f);
          aq[r] = fmaf(t, wo, aq[r]);
          aA[r] = fmaf(dt * cA2[r], wo, aA[r]);
          aB[r] = fmaf(dt * cA3[r], wo, aB[r]);
        }
      }
      // reduce across 16 col-lanes (DPP, VALU pipe)
#pragma unroll
      for (int r = 0; r < 4; ++r){
        aq[r] = row16_sum(aq[r]);
        aA[r] = row16_sum(aA[r]);
        aB[r] = row16_sum(aB[r]);
      }
      // source-side r-select (SSA ternaries -> cndmask, no array indexing)
      float qsel = (colL & 2) ? ((colL & 1) ? aq[3] : aq[2])
                              : ((colL & 1) ? aq[1] : aq[0]);
      float asel = (colL & 2) ? ((colL & 1) ? aA[3] : aA[2])
                              : ((colL & 1) ? aA[1] : aA[0]);
      float bsel = (colL & 2) ? ((colL & 1) ? aB[3] : aB[2])
                              : ((colL & 1) ? aB[1] : aB[0]);
      // pull sample (st*16+colL)'s value from group colL>>2
      float qp = __shfl(qsel, srcL, 64);
      float ap = __shfl(asel, srcL, 64);
      float bp = __shfl(bsel, srcL, 64);
      bool keep = (st == grp);
      qraw[hd] = keep ? qp : qraw[hd];
      Araw[hd] = keep ? ap : Araw[hd];
      Braw[hd] = keep ? bp : Braw[hd];
    }
  }

  const float SIG = 0.03f;
  q1o = __expf(qraw[0] + bo_v[0]);
  q2o = __expf(qraw[1] + bo_v[1]);
  q3o = __expf(qraw[2] + bo_v[2]);
  s11 = SIG * Araw[0]; s21 = SIG * Araw[1]; s31 = SIG * Araw[2];
  s12 = SIG * Braw[0]; s22 = SIG * Braw[1]; s32 = SIG * Braw[2];
}

// NOTE: no min-waves __launch_bounds__ arg — it forces accumulator spills
// ((256,3)->210GB, (256,4)->42GB scratch writes). Natural allocation is clean.
__global__ __launch_bounds__(NB)
void sim_kernel(const float* __restrict__ Y,
  const float* __restrict__ W0,  const float* __restrict__ b0,
  const float* __restrict__ Wh1, const float* __restrict__ bh1,
  const float* __restrict__ Wo1, const float* __restrict__ bo1,
  const float* __restrict__ Wh2, const float* __restrict__ bh2,
  const float* __restrict__ Wo2, const float* __restrict__ bo2,
  const float* __restrict__ Wh3, const float* __restrict__ bh3,
  const float* __restrict__ Wo3, const float* __restrict__ bo3,
  float* __restrict__ out, int n)
{
  // B matrices: per head {Wh^T, (diag(w0a)Wh)^T, (diag(w0b)Wh)^T}, bf16,
  // swizzled rows of 128B. 288 rows = 36 KB.
  __shared__ __align__(16) char sB[288 * 128];
  __shared__ __align__(16) char sA[4][2 * 16 * 128];   // per-wave {h,u} (16 KB)

  for (int e = threadIdx.x; e < 18432; e += NB){
    int hd   = e / 6144;
    int rem  = e - hd * 6144;
    int mat  = rem >> 11;          // 0=Wh, 1=w0a-scaled, 2=w0b-scaled
    int rem2 = rem & 2047;
    int j = rem2 >> 5, i = rem2 & 31;
    const float* W = (hd == 0) ? Wh1 : (hd == 1) ? Wh2 : Wh3;
    float wh = W[j * 32 + i];
    float v  = (mat == 0) ? wh : (mat == 1) ? W0[j] * wh : W0[64 + j] * wh;
    int R   = hd * 96 + mat * 32 + i;
    int off = (R * 128 + j * 2) ^ ((R & 7) << 4);
    *(unsigned short*)(sB + off) = (unsigned short)f2bfbits(v);
  }
  __syncthreads();

  const int wv   = threadIdx.x >> 6;
  const int lane = threadIdx.x & 63;
  const int colL = lane & 15;
  const int grp  = lane >> 4;
  char* sAw = &sA[wv][0];

  // per-lane second-layer constants (scalars in regs — R6-proven safe)
  float bh_v[3][2], wo_v[3][2], bo_v[3];
  {
    const float* BH[3] = {bh1, bh2, bh3};
    const float* WOp[3] = {Wo1, Wo2, Wo3};
#pragma unroll
    for (int hd = 0; hd < 3; ++hd)
#pragma unroll
      for (int nt = 0; nt < 2; ++nt){
        bh_v[hd][nt] = BH[hd][nt*16 + colL];
        wo_v[hd][nt] = WOp[hd][nt*16 + colL];
      }
    bo_v[0] = bo1[0]; bo_v[1] = bo2[0]; bo_v[2] = bo3[0];
  }

  const int gid = blockIdx.x * NB + threadIdx.x;
  const int ii  = (gid < n) ? gid : (n - 1);
  const float valid = (gid < n) ? 1.0f : 0.0f;

  const float2 yv = ((const float2*)Y)[ii];
  const float y2 = yv.x, y3 = yv.y;

  const float GAMMA = 1.2f, DT = 0.005f, SIGMA = 0.03f;
  const float KAPPA = 0.2f, YBAR = 2.0f, RHO = 0.03f, Bc = 1.0f, Cc = 0.1f;

  float q1,q2,q3,s11,s21,s31,s12,s22,s32;
  net_eval(y2, y3, W0, b0, sAw, sB, colL, grp, bh_v, wo_v, bo_v,
           q1,q2,q3,s11,s21,s31,s12,s22,s32);
  float Y2 = y2, Y3 = y3;
  float loss = 0.0f;

  for (int t = 0; t < PERIOD; ++t){
    // --- noise: threefry rollout, counter = flat index (bit-exact) ---
    uint32_t idx0 = 2u * ((uint32_t)t * (uint32_t)n + (uint32_t)ii);
    uint32_t a0, a1, c0, c1;
    threefry2x32_k42(0u, idx0,      a0, a1);
    threefry2x32_k42(0u, idx0 + 1u, c0, c1);
    float dZ1 = 0.070710678f * normal_from_bits(a0 ^ a1);
    float dZ2 = 0.070710678f * normal_from_bits(c0 ^ c1);

    // --- step math (mirror reference, f32) ---
    float Wt  = q1 + q2 + q3;
    float q1h = q1 / Wt;
    float q2h = q2 / Wt;
    float q3h = 1.0f - q1h - q2h;
    float q1sq = q1 * q1;
    float c   = Bc*q1 - Cc*q1sq + Y2 + Y3;
    float bq  = Bc*q1 - 2.0f*Cc*q1sq;
    float sc1 = fmaf(bq, s11, SIGMA);
    float sc2 = fmaf(bq, s12, SIGMA);
    float sW1 = q1*s11 + q2*s21 + q3*s31;
    float sW2 = q1*s12 + q2*s22 + q3*s32;
    float sJ1 = 6.0f * (sc1/c - sW1/Wt);
    float sJ2 = 6.0f * (sc2/c - sW2/Wt);
    float d11 = s11*s11 + s12*s12;
    float d12 = s11*s21 + s12*s22;
    float d13 = s11*s31 + s12*s32;
    float d22 = s21*s21 + s22*s22;
    float d23 = s21*s31 + s22*s32;
    float d33 = s31*s31 + s32*s32;
    const float oneMG = 1.0f - GAMMA;   // -0.2
    float p1 = GAMMA*(q1h*d11 + q2h*d12 + q3h*d13) - oneMG*(sJ1*s11 + sJ2*s12);
    float p2 = GAMMA*(q1h*d12 + q2h*d22 + q3h*d23) - oneMG*(sJ1*s21 + sJ2*s22);
    float p3 = GAMMA*(q1h*d13 + q2h*d23 + q3h*d33) - oneMG*(sJ1*s31 + sJ2*s32);
    float muY2 = KAPPA * (YBAR - Y2);
    float muY3 = KAPPA * (YBAR - Y3);
    float r = RHO + GAMMA*(bq*(p1 - (Bc - Cc*q1)) - Cc*q1sq*d11 + muY2 + muY3)/c
                  - 1.32f*(sc1*sc1 + sc2*sc2)/(c*c);
    r = r / (1.0f - GAMMA*bq/c);
    float mu1 = r + p1 - (Bc - Cc*q1);
    float mu2 = r + p2 - Y2/q2;
    float mu3 = r + p3 - Y3/q3;
    float q1n = q1 * (1.0f + mu1*DT + s11*dZ1 + s12*dZ2);
    float q2n = q2 * (1.0f + mu2*DT + s21*dZ1 + s22*dZ2);
    float q3n = q3 * (1.0f + mu3*DT + s31*dZ1 + s32*dZ2);
    float Y2n = Y2 + muY2*DT + SIGMA*dZ1;
    float Y3n = Y3 + muY3*DT + SIGMA*dZ2;

    float qt1, qt2, qt3;
    net_eval(Y2n, Y3n, W0, b0, sAw, sB, colL, grp, bh_v, wo_v, bo_v,
             qt1,qt2,qt3, s11,s21,s31,s12,s22,s32);

    float e1 = q1n - qt1, e2 = q2n - qt2, e3 = q3n - qt3;
    loss += e1*e1 + e2*e2 + e3*e3;

    q1 = q1n; q2 = q2n; q3 = q3n; Y2 = Y2n; Y3 = Y3n;
  }

  loss *= valid * (1.0f / ((float)15000000));   // / (n * PERIOD)

  // --- block reduction -> one atomic per block ---
#pragma unroll
  for (int off = 32; off > 0; off >>= 1)
    loss += __shfl_down(loss, off, 64);
  __shared__ float sred[NB / 64];
  if (lane == 0) sred[wv] = loss;
  __syncthreads();
  if (threadIdx.x == 0){
    float s = 0.0f;
#pragma unroll
    for (int w = 0; w < NB / 64; ++w) s += sred[w];
    atomicAdd(out, s);
  }
}

extern "C" void kernel_launch(void* const* d_in, const int* in_sizes, int n_in,
                              void* d_out, int out_size, void* d_ws, size_t ws_size,
                              hipStream_t stream)
{
  const float* Y   = (const float*)d_in[0];
  const float* W0  = (const float*)d_in[1];
  const float* b0  = (const float*)d_in[2];
  const float* Wh1 = (const float*)d_in[3];
  const float* bh1 = (const float*)d_in[4];
  const float* Wo1 = (const float*)d_in[5];
  const float* bo1 = (const float*)d_in[6];
  const float* Wh2 = (const float*)d_in[7];
  const float* bh2 = (const float*)d_in[8];
  const float* Wo2 = (const float*)d_in[9];
  const float* bo2 = (const float*)d_in[10];
  const float* Wh3 = (const float*)d_in[11];
  const float* bh3 = (const float*)d_in[12];
  const float* Wo3 = (const float*)d_in[13];
  const float* bo3 = (const float*)d_in[14];

  const int n = in_sizes[0] / 2;

  (void)hipMemsetAsync(d_out, 0, sizeof(float), stream);

  const int grid = (n + NB - 1) / NB;
  sim_kernel<<<grid, NB, 0, stream>>>(Y,
      W0, b0, Wh1, bh1, Wo1, bo1, Wh2, bh2, Wo2, bo2, Wh3, bh3, Wo3, bo3,
      (float*)d_out, n);
}

// Round 14
// 2567.116 us; speedup vs baseline: 2.8182x; 1.0519x over previous
//
#include <hip/hip_runtime.h>
#include <hip/hip_bf16.h>
#include <stdint.h>

#define NB 256
#define PERIOD 30

typedef __bf16  bf16x8 __attribute__((ext_vector_type(8)));
typedef float   f32x4  __attribute__((ext_vector_type(4)));
typedef float   f32x2  __attribute__((ext_vector_type(2)));
typedef unsigned int uint4v __attribute__((ext_vector_type(4)));

__device__ __forceinline__ float frcp(float x){ return __builtin_amdgcn_rcpf(x); }

// tanh(x) = 1 - 2/(exp(2x)+1)
__device__ __forceinline__ float fast_tanh(float x){
  float e = __expf(2.0f*x);
  return fmaf(-2.0f, frcp(e + 1.0f), 1.0f);
}

__device__ __forceinline__ unsigned int f2bfbits(float x){
  union { __hip_bfloat16 b; unsigned short u; } v;
  v.b = __float2bfloat16(x);          // RNE, matches XLA convert
  return (unsigned int)v.u;
}
__device__ __forceinline__ unsigned int pack2bf(float lo, float hi){
  return f2bfbits(lo) | (f2bfbits(hi) << 16);
}

// 16-lane row-sum on the VALU pipe (v_add_f32_dpp); dpp_ctrl must be an
// immediate -> template parameter.
template <int CTRL>
__device__ __forceinline__ float dpp_add_step(float x){
  int y = __builtin_amdgcn_update_dpp(0, __float_as_int(x), CTRL, 0xf, 0xf, true);
  return x + __int_as_float(y);
}
__device__ __forceinline__ float row16_sum(float x){
  x = dpp_add_step<0xB1>(x);    // quad_perm [1,0,3,2]  (xor 1)
  x = dpp_add_step<0x4E>(x);    // quad_perm [2,3,0,1]  (xor 2)
  x = dpp_add_step<0x124>(x);   // row_ror:4
  x = dpp_add_step<0x128>(x);   // row_ror:8
  return x;                     // all 16 row-lanes hold the row sum
}

// Threefry-2x32, 20 rounds, key = (0, 42)
__device__ __forceinline__ void threefry2x32_k42(uint32_t x0, uint32_t x1,
                                                 uint32_t& o0, uint32_t& o1){
  const uint32_t ks0 = 0u, ks1 = 42u, ks2 = 0u ^ 42u ^ 0x1BD11BDAu;
  x0 += ks0; x1 += ks1;
#define TFR(rot) { x0 += x1; x1 = (x1 << (rot)) | (x1 >> (32 - (rot))); x1 ^= x0; }
  TFR(13) TFR(15) TFR(26) TFR(6)
  x0 += ks1; x1 += ks2 + 1u;
  TFR(17) TFR(29) TFR(16) TFR(24)
  x0 += ks2; x1 += ks0 + 2u;
  TFR(13) TFR(15) TFR(26) TFR(6)
  x0 += ks0; x1 += ks1 + 3u;
  TFR(17) TFR(29) TFR(16) TFR(24)
  x0 += ks1; x1 += ks2 + 4u;
  TFR(13) TFR(15) TFR(26) TFR(6)
  x0 += ks2; x1 += ks0 + 5u;
#undef TFR
  o0 = x0; o1 = x1;
}

// Mirror jax.random.normal f32 (XLA erfinv polynomial)
__device__ __forceinline__ float normal_from_bits(uint32_t bits){
  float f = __uint_as_float((bits >> 9) | 0x3f800000u) - 1.0f;
  const float lo = -0.99999994f;
  float u = fmaf(f, 2.0f, lo);
  u = fmaxf(u, lo);
  float w = -log1pf(-u*u);
  float p;
  if (w < 5.0f){
    float ww = w - 2.5f;
    p = 2.81022636e-08f;
    p = fmaf(p, ww, 3.43273939e-07f);
    p = fmaf(p, ww, -3.5233877e-06f);
    p = fmaf(p, ww, -4.39150654e-06f);
    p = fmaf(p, ww, 0.00021858087f);
    p = fmaf(p, ww, -0.00125372503f);
    p = fmaf(p, ww, -0.00417768164f);
    p = fmaf(p, ww, 0.246640727f);
    p = fmaf(p, ww, 1.50140941f);
  } else {
    float ww = sqrtf(w) - 3.0f;
    p = -0.000200214257f;
    p = fmaf(p, ww, 0.000100950558f);
    p = fmaf(p, ww, 0.00134934322f);
    p = fmaf(p, ww, -0.00367342844f);
    p = fmaf(p, ww, 0.00573950773f);
    p = fmaf(p, ww, -0.0076224613f);
    p = fmaf(p, ww, 0.00943887047f);
    p = fmaf(p, ww, 1.00167406f);
    p = fmaf(p, ww, 2.83297682f);
  }
  return 1.41421356f * (p * u);
}

// stage one sample-tile's h/u rows (owners = lanes with grp==st)
__device__ __forceinline__ void stage_tile(char* buf, int st, int grp, int colL,
    const unsigned int* hp, const unsigned int* up){
  if (grp == st){
    const int rbase = colL * 128;
    const int sw = (colL & 7) << 4;
#pragma unroll
    for (int w = 0; w < 8; ++w){
      int off = rbase + ((w * 16) ^ sw);
      *(uint4v*)(buf + off)        = uint4v{hp[w*4], hp[w*4+1], hp[w*4+2], hp[w*4+3]};
      *(uint4v*)(buf + 2048 + off) = uint4v{up[w*4], up[w*4+1], up[w*4+2], up[w*4+3]};
    }
  }
}

// MFMA net eval with folded JVP weights. B matrices per head:
//   mat0 = Wh^T                       (q path; wo stays f32 — tanh blocks fold)
//   mat1 = (diag(w0a)·Wh·diag(wo·SIG))^T   -> cA2 emerges wo- and SIG-scaled
//   mat2 = (diag(w0b)·Wh·diag(wo·SIG))^T
// Tail accumulators run as f32x2 (v_pk_fma_f32). DPP reduce (VALU pipe);
// shfl redistribute. VGPR must stay <= 170 (3 waves/SIMD boundary) — no
// st-loop unroll (keep #pragma unroll 1).
__device__ __forceinline__ void net_eval(
    float y2, float y3,
    const float* __restrict__ W0, const float* __restrict__ b0,
    char* sAw,                        // this wave's A buffer: [2][16][128B]
    const char* __restrict__ sBb,     // B matrices [3hd][3mat][32n][128B]
    int colL, int grp,
    const float (&bh_v)[3][2], const float (&wo_v)[3][2], const float* bo_v,
    float& q1o, float& q2o, float& q3o,
    float& s11, float& s21, float& s31,
    float& s12, float& s22, float& s32)
{
  // ---- first layer (f32x2 pairs, per-lane = per-sample): h and u packs ----
  unsigned int hp[32], up[32];
#pragma unroll
  for (int d = 0; d < 32; ++d){
    f32x2 w0a = *(const f32x2*)(W0 + 2*d);
    f32x2 w0b = *(const f32x2*)(W0 + 64 + 2*d);
    f32x2 b0v = *(const f32x2*)(b0 + 2*d);
    f32x2 pre = y2 * w0a + (y3 * w0b + b0v);      // v_pk_fma_f32 x2
    float hA = fast_tanh(pre.x), hB = fast_tanh(pre.y);
    f32x2 h  = {hA, hB};
    f32x2 u  = 1.0f - h * h;                      // v_pk_fma path
    hp[d] = pack2bf(hA, hB);
    up[d] = pack2bf(u.x, u.y);
  }

  float qraw[3] = {0,0,0}, Araw[3] = {0,0,0}, Braw[3] = {0,0,0};
  const int bsw  = (colL & 7) << 4;
  const int srcL = ((colL >> 2) << 4) | colL;   // shfl source lane

#pragma unroll 1
  for (int st = 0; st < 4; ++st){
    // stage this tile in-place (same-wave program order -> overwrite safe)
    stage_tile(sAw, st, grp, colL, hp, up);

    // A fragments for this tile
    bf16x8 afh[2], afu[2];
#pragma unroll
    for (int kt = 0; kt < 2; ++kt){
      int off = colL*128 + ((kt*64 + grp*16) ^ bsw);
      afh[kt] = *(const bf16x8*)(sAw + off);
      afu[kt] = *(const bf16x8*)(sAw + 2048 + off);
    }

#pragma unroll
    for (int hd = 0; hd < 3; ++hd){
      f32x2 aq01 = {0,0}, aq23 = {0,0};
      f32x2 aA01 = {0,0}, aA23 = {0,0};
      f32x2 aB01 = {0,0}, aB23 = {0,0};
#pragma unroll
      for (int nt = 0; nt < 2; ++nt){
        // B fragments (3 matrices) from LDS at point of use
        bf16x8 bW[2], bA[2], bB[2];
#pragma unroll
        for (int kt = 0; kt < 2; ++kt){
          int rbase2 = (hd*96 + nt*16 + colL) * 128;
          int ko = ((kt*64 + grp*16) ^ bsw);
          bW[kt] = *(const bf16x8*)(sBb + rbase2 + ko);
          bA[kt] = *(const bf16x8*)(sBb + rbase2 + 4096 + ko);
          bB[kt] = *(const bf16x8*)(sBb + rbase2 + 8192 + ko);
        }
        f32x4 cAT = {0,0,0,0}, cA2 = {0,0,0,0}, cA3 = {0,0,0,0};
#pragma unroll
        for (int kt = 0; kt < 2; ++kt){
          cAT = __builtin_amdgcn_mfma_f32_16x16x32_bf16(afh[kt], bW[kt], cAT, 0, 0, 0);
          cA2 = __builtin_amdgcn_mfma_f32_16x16x32_bf16(afu[kt], bA[kt], cA2, 0, 0, 0);
          cA3 = __builtin_amdgcn_mfma_f32_16x16x32_bf16(afu[kt], bB[kt], cA3, 0, 0, 0);
        }
        float bh = bh_v[hd][nt], wo = wo_v[hd][nt];
        float t0 = fast_tanh(cAT[0] + bh);
        float t1 = fast_tanh(cAT[1] + bh);
        float t2 = fast_tanh(cAT[2] + bh);
        float t3 = fast_tanh(cAT[3] + bh);
        f32x2 dt01 = {fmaf(-t0, t0, 1.0f), fmaf(-t1, t1, 1.0f)};
        f32x2 dt23 = {fmaf(-t2, t2, 1.0f), fmaf(-t3, t3, 1.0f)};
        f32x2 wo2 = {wo, wo};
        aq01 = aq01 + f32x2{t0, t1} * wo2;                 // pk_fma
        aq23 = aq23 + f32x2{t2, t3} * wo2;
        aA01 = aA01 + dt01 * f32x2{cA2[0], cA2[1]};        // wo*SIG folded in B
        aA23 = aA23 + dt23 * f32x2{cA2[2], cA2[3]};
        aB01 = aB01 + dt01 * f32x2{cA3[0], cA3[1]};
        aB23 = aB23 + dt23 * f32x2{cA3[2], cA3[3]};
      }
      // reduce across 16 col-lanes (DPP, VALU pipe)
      float rq0 = row16_sum(aq01.x), rq1 = row16_sum(aq01.y);
      float rq2 = row16_sum(aq23.x), rq3 = row16_sum(aq23.y);
      float rA0 = row16_sum(aA01.x), rA1 = row16_sum(aA01.y);
      float rA2 = row16_sum(aA23.x), rA3 = row16_sum(aA23.y);
      float rB0 = row16_sum(aB01.x), rB1 = row16_sum(aB01.y);
      float rB2 = row16_sum(aB23.x), rB3 = row16_sum(aB23.y);
      // source-side r-select (SSA ternaries -> cndmask)
      float qsel = (colL & 2) ? ((colL & 1) ? rq3 : rq2)
                              : ((colL & 1) ? rq1 : rq0);
      float asel = (colL & 2) ? ((colL & 1) ? rA3 : rA2)
                              : ((colL & 1) ? rA1 : rA0);
      float bsel = (colL & 2) ? ((colL & 1) ? rB3 : rB2)
                              : ((colL & 1) ? rB1 : rB0);
      // pull sample (st*16+colL)'s value from group colL>>2
      float qp = __shfl(qsel, srcL, 64);
      float ap = __shfl(asel, srcL, 64);
      float bp = __shfl(bsel, srcL, 64);
      bool keep = (st == grp);
      qraw[hd] = keep ? qp : qraw[hd];
      Araw[hd] = keep ? ap : Araw[hd];
      Braw[hd] = keep ? bp : Braw[hd];
    }
  }

  q1o = __expf(qraw[0] + bo_v[0]);
  q2o = __expf(qraw[1] + bo_v[1]);
  q3o = __expf(qraw[2] + bo_v[2]);
  s11 = Araw[0]; s21 = Araw[1]; s31 = Araw[2];   // SIG folded into B
  s12 = Braw[0]; s22 = Braw[1]; s32 = Braw[2];
}

// NOTE: no min-waves __launch_bounds__ arg — it forces accumulator spills
// ((256,3)->210GB, (256,4)->42GB scratch writes). Natural allocation is clean.
__global__ __launch_bounds__(NB)
void sim_kernel(const float* __restrict__ Y,
  const float* __restrict__ W0,  const float* __restrict__ b0,
  const float* __restrict__ Wh1, const float* __restrict__ bh1,
  const float* __restrict__ Wo1, const float* __restrict__ bo1,
  const float* __restrict__ Wh2, const float* __restrict__ bh2,
  const float* __restrict__ Wo2, const float* __restrict__ bo2,
  const float* __restrict__ Wh3, const float* __restrict__ bh3,
  const float* __restrict__ Wo3, const float* __restrict__ bo3,
  float* __restrict__ out, int n)
{
  // B matrices: per head {Wh^T, (diag(w0a)Wh diag(wo*SIG))^T,
  // (diag(w0b)Wh diag(wo*SIG))^T}, bf16, swizzled 128B rows. 288 rows = 36 KB.
  __shared__ __align__(16) char sB[288 * 128];
  __shared__ __align__(16) char sA[4][2 * 16 * 128];   // per-wave {h,u} (16 KB)

  for (int e = threadIdx.x; e < 18432; e += NB){
    int hd   = e / 6144;
    int rem  = e - hd * 6144;
    int mat  = rem >> 11;          // 0=Wh, 1=w0a-scaled, 2=w0b-scaled
    int rem2 = rem & 2047;
    int j = rem2 >> 5, i = rem2 & 31;
    const float* W  = (hd == 0) ? Wh1 : (hd == 1) ? Wh2 : Wh3;
    const float* WO = (hd == 0) ? Wo1 : (hd == 1) ? Wo2 : Wo3;
    float wh = W[j * 32 + i];
    float sc = WO[i] * 0.03f;      // wo * SIGMA fold (JVP mats only)
    float v  = (mat == 0) ? wh
             : (mat == 1) ? W0[j] * wh * sc
                          : W0[64 + j] * wh * sc;
    int R   = hd * 96 + mat * 32 + i;
    int off = (R * 128 + j * 2) ^ ((R & 7) << 4);
    *(unsigned short*)(sB + off) = (unsigned short)f2bfbits(v);
  }
  __syncthreads();

  const int wv   = threadIdx.x >> 6;
  const int lane = threadIdx.x & 63;
  const int colL = lane & 15;
  const int grp  = lane >> 4;
  char* sAw = &sA[wv][0];

  // per-lane second-layer constants (scalars in regs — R6-proven safe)
  float bh_v[3][2], wo_v[3][2], bo_v[3];
  {
    const float* BH[3] = {bh1, bh2, bh3};
    const float* WOp[3] = {Wo1, Wo2, Wo3};
#pragma unroll
    for (int hd = 0; hd < 3; ++hd)
#pragma unroll
      for (int nt = 0; nt < 2; ++nt){
        bh_v[hd][nt] = BH[hd][nt*16 + colL];
        wo_v[hd][nt] = WOp[hd][nt*16 + colL];
      }
    bo_v[0] = bo1[0]; bo_v[1] = bo2[0]; bo_v[2] = bo3[0];
  }

  const int gid = blockIdx.x * NB + threadIdx.x;
  const int ii  = (gid < n) ? gid : (n - 1);
  const float valid = (gid < n) ? 1.0f : 0.0f;

  const float2 yv = ((const float2*)Y)[ii];
  const float y2 = yv.x, y3 = yv.y;

  const float GAMMA = 1.2f, DT = 0.005f, SIGMA = 0.03f;
  const float KAPPA = 0.2f, YBAR = 2.0f, RHO = 0.03f, Bc = 1.0f, Cc = 0.1f;

  float q1,q2,q3,s11,s21,s31,s12,s22,s32;
  net_eval(y2, y3, W0, b0, sAw, sB, colL, grp, bh_v, wo_v, bo_v,
           q1,q2,q3,s11,s21,s31,s12,s22,s32);
  float Y2 = y2, Y3 = y3;
  float loss = 0.0f;

  for (int t = 0; t < PERIOD; ++t){
    // --- noise: threefry rollout, counter = flat index (bit-exact) ---
    uint32_t idx0 = 2u * ((uint32_t)t * (uint32_t)n + (uint32_t)ii);
    uint32_t a0, a1, c0, c1;
    threefry2x32_k42(0u, idx0,      a0, a1);
    threefry2x32_k42(0u, idx0 + 1u, c0, c1);
    float dZ1 = 0.070710678f * normal_from_bits(a0 ^ a1);
    float dZ2 = 0.070710678f * normal_from_bits(c0 ^ c1);

    // --- step math (mirror reference, f32) ---
    float Wt  = q1 + q2 + q3;
    float q1h = q1 / Wt;
    float q2h = q2 / Wt;
    float q3h = 1.0f - q1h - q2h;
    float q1sq = q1 * q1;
    float c   = Bc*q1 - Cc*q1sq + Y2 + Y3;
    float bq  = Bc*q1 - 2.0f*Cc*q1sq;
    float sc1 = fmaf(bq, s11, SIGMA);
    float sc2 = fmaf(bq, s12, SIGMA);
    float sW1 = q1*s11 + q2*s21 + q3*s31;
    float sW2 = q1*s12 + q2*s22 + q3*s32;
    float sJ1 = 6.0f * (sc1/c - sW1/Wt);
    float sJ2 = 6.0f * (sc2/c - sW2/Wt);
    float d11 = s11*s11 + s12*s12;
    float d12 = s11*s21 + s12*s22;
    float d13 = s11*s31 + s12*s32;
    float d22 = s21*s21 + s22*s22;
    float d23 = s21*s31 + s22*s32;
    float d33 = s31*s31 + s32*s32;
    const float oneMG = 1.0f - GAMMA;   // -0.2
    float p1 = GAMMA*(q1h*d11 + q2h*d12 + q3h*d13) - oneMG*(sJ1*s11 + sJ2*s12);
    float p2 = GAMMA*(q1h*d12 + q2h*d22 + q3h*d23) - oneMG*(sJ1*s21 + sJ2*s22);
    float p3 = GAMMA*(q1h*d13 + q2h*d23 + q3h*d33) - oneMG*(sJ1*s31 + sJ2*s32);
    float muY2 = KAPPA * (YBAR - Y2);
    float muY3 = KAPPA * (YBAR - Y3);
    float r = RHO + GAMMA*(bq*(p1 - (Bc - Cc*q1)) - Cc*q1sq*d11 + muY2 + muY3)/c
                  - 1.32f*(sc1*sc1 + sc2*sc2)/(c*c);
    r = r / (1.0f - GAMMA*bq/c);
    float mu1 = r + p1 - (Bc - Cc*q1);
    float mu2 = r + p2 - Y2/q2;
    float mu3 = r + p3 - Y3/q3;
    float q1n = q1 * (1.0f + mu1*DT + s11*dZ1 + s12*dZ2);
    float q2n = q2 * (1.0f + mu2*DT + s21*dZ1 + s22*dZ2);
    float q3n = q3 * (1.0f + mu3*DT + s31*dZ1 + s32*dZ2);
    float Y2n = Y2 + muY2*DT + SIGMA*dZ1;
    float Y3n = Y3 + muY3*DT + SIGMA*dZ2;

    float qt1, qt2, qt3;
    net_eval(Y2n, Y3n, W0, b0, sAw, sB, colL, grp, bh_v, wo_v, bo_v,
             qt1,qt2,qt3, s11,s21,s31,s12,s22,s32);

    float e1 = q1n - qt1, e2 = q2n - qt2, e3 = q3n - qt3;
    loss += e1*e1 + e2*e2 + e3*e3;

    q1 = q1n; q2 = q2n; q3 = q3n; Y2 = Y2n; Y3 = Y3n;
  }

  loss *= valid * (1.0f / ((float)15000000));   // / (n * PERIOD)

  // --- block reduction -> one atomic per block ---
#pragma unroll
  for (int off = 32; off > 0; off >>= 1)
    loss += __shfl_down(loss, off, 64);
  __shared__ float sred[NB / 64];
  if (lane == 0) sred[wv] = loss;
  __syncthreads();
  if (threadIdx.x == 0){
    float s = 0.0f;
#pragma unroll
    for (int w = 0; w < NB / 64; ++w) s += sred[w];
    atomicAdd(out, s);
  }
}

extern "C" void kernel_launch(void* const* d_in, const int* in_sizes, int n_in,
                              void* d_out, int out_size, void* d_ws, size_t ws_size,
                              hipStream_t stream)
{
  const float* Y   = (const float*)d_in[0];
  const float* W0  = (const float*)d_in[1];
  const float* b0  = (const float*)d_in[2];
  const float* Wh1 = (const float*)d_in[3];
  const float* bh1 = (const float*)d_in[4];
  const float* Wo1 = (const float*)d_in[5];
  const float* bo1 = (const float*)d_in[6];
  const float* Wh2 = (const float*)d_in[7];
  const float* bh2 = (const float*)d_in[8];
  const float* Wo2 = (const float*)d_in[9];
  const float* bo2 = (const float*)d_in[10];
  const float* Wh3 = (const float*)d_in[11];
  const float* bh3 = (const float*)d_in[12];
  const float* Wo3 = (const float*)d_in[13];
  const float* bo3 = (const float*)d_in[14];

  const int n = in_sizes[0] / 2;

  (void)hipMemsetAsync(d_out, 0, sizeof(float), stream);

  const int grid = (n + NB - 1) / NB;
  sim_kernel<<<grid, NB, 0, stream>>>(Y,
      W0, b0, Wh1, bh1, Wo1, bo1, Wh2, bh2, Wo2, bo2, Wh3, bh3, Wo3, bo3,
      (float*)d_out, n);
}

// Round 15
// 2207.291 us; speedup vs baseline: 3.2776x; 1.1630x over previous
//
#include <hip/hip_runtime.h>
#include <hip/hip_bf16.h>
#include <stdint.h>

#define NB 256
#define PERIOD 30

typedef __bf16  bf16x8 __attribute__((ext_vector_type(8)));
typedef float   f32x4  __attribute__((ext_vector_type(4)));
typedef float   f32x2  __attribute__((ext_vector_type(2)));
typedef unsigned int uint4v __attribute__((ext_vector_type(4)));

__device__ __forceinline__ float frcp(float x){ return __builtin_amdgcn_rcpf(x); }

// tanh(x) = 1 - 2/(exp(2x)+1)
__device__ __forceinline__ float fast_tanh(float x){
  float e = __expf(2.0f*x);
  return fmaf(-2.0f, frcp(e + 1.0f), 1.0f);
}

__device__ __forceinline__ unsigned int f2bfbits(float x){
  union { __hip_bfloat16 b; unsigned short u; } v;
  v.b = __float2bfloat16(x);          // RNE, matches XLA convert
  return (unsigned int)v.u;
}
__device__ __forceinline__ unsigned int pack2bf(float lo, float hi){
  return f2bfbits(lo) | (f2bfbits(hi) << 16);
}

// Threefry-2x32, 20 rounds, key = (0, 42)
__device__ __forceinline__ void threefry2x32_k42(uint32_t x0, uint32_t x1,
                                                 uint32_t& o0, uint32_t& o1){
  const uint32_t ks0 = 0u, ks1 = 42u, ks2 = 0u ^ 42u ^ 0x1BD11BDAu;
  x0 += ks0; x1 += ks1;
#define TFR(rot) { x0 += x1; x1 = (x1 << (rot)) | (x1 >> (32 - (rot))); x1 ^= x0; }
  TFR(13) TFR(15) TFR(26) TFR(6)
  x0 += ks1; x1 += ks2 + 1u;
  TFR(17) TFR(29) TFR(16) TFR(24)
  x0 += ks2; x1 += ks0 + 2u;
  TFR(13) TFR(15) TFR(26) TFR(6)
  x0 += ks0; x1 += ks1 + 3u;
  TFR(17) TFR(29) TFR(16) TFR(24)
  x0 += ks1; x1 += ks2 + 4u;
  TFR(13) TFR(15) TFR(26) TFR(6)
  x0 += ks2; x1 += ks0 + 5u;
#undef TFR
  o0 = x0; o1 = x1;
}

// Mirror jax.random.normal f32 (XLA erfinv polynomial)
__device__ __forceinline__ float normal_from_bits(uint32_t bits){
  float f = __uint_as_float((bits >> 9) | 0x3f800000u) - 1.0f;
  const float lo = -0.99999994f;
  float u = fmaf(f, 2.0f, lo);
  u = fmaxf(u, lo);
  float w = -log1pf(-u*u);
  float p;
  if (w < 5.0f){
    float ww = w - 2.5f;
    p = 2.81022636e-08f;
    p = fmaf(p, ww, 3.43273939e-07f);
    p = fmaf(p, ww, -3.5233877e-06f);
    p = fmaf(p, ww, -4.39150654e-06f);
    p = fmaf(p, ww, 0.00021858087f);
    p = fmaf(p, ww, -0.00125372503f);
    p = fmaf(p, ww, -0.00417768164f);
    p = fmaf(p, ww, 0.246640727f);
    p = fmaf(p, ww, 1.50140941f);
  } else {
    float ww = sqrtf(w) - 3.0f;
    p = -0.000200214257f;
    p = fmaf(p, ww, 0.000100950558f);
    p = fmaf(p, ww, 0.00134934322f);
    p = fmaf(p, ww, -0.00367342844f);
    p = fmaf(p, ww, 0.00573950773f);
    p = fmaf(p, ww, -0.0076224613f);
    p = fmaf(p, ww, 0.00943887047f);
    p = fmaf(p, ww, 1.00167406f);
    p = fmaf(p, ww, 2.83297682f);
  }
  return 1.41421356f * (p * u);
}

// stage one sample-tile's h/u rows (owners = lanes with grp==st)
__device__ __forceinline__ void stage_tile(char* buf, int st, int grp, int colL,
    const unsigned int* hp, const unsigned int* up){
  if (grp == st){
    const int rbase = colL * 128;
    const int sw = (colL & 7) << 4;
#pragma unroll
    for (int w = 0; w < 8; ++w){
      int off = rbase + ((w * 16) ^ sw);
      *(uint4v*)(buf + off)        = uint4v{hp[w*4], hp[w*4+1], hp[w*4+2], hp[w*4+3]};
      *(uint4v*)(buf + 2048 + off) = uint4v{up[w*4], up[w*4+1], up[w*4+2], up[w*4+3]};
    }
  }
}

// MFMA net eval, C[n, sample] orientation: A-operand = B-matrix rows (n),
// B-operand = staged h/u sample columns. Fragment ADDRESSING is identical to
// R14 (A/B lane layouts are symmetric for 16x16x32) — only the mfma argument
// order differs. Gains vs R14: the n-reduction over r/nt is IN-LANE (the tail
// fma accumulation), leaving only 2 shfl_xor(16,32) per value (replaces 48
// v_add_dpp + select chain per (st,hd)); bh folded in via the MFMA C-seed.
// bh/wo come from LDS per (hd,nt) use (avoids +48 long-lived VGPRs; R7
// lesson about hoisting LDS data to long-lived regs).
__device__ __forceinline__ void net_eval(
    float y2, float y3,
    const float* __restrict__ W0, const float* __restrict__ b0,
    char* sAw,                        // this wave's A buffer: [2][16][128B]
    const char* __restrict__ sBb,     // B matrices [3hd][3mat][32n][128B]
    const float* __restrict__ sBH,    // [3][32] f32 bh
    const float* __restrict__ sWO,    // [3][32] f32 wo
    int colL, int grp,
    const float* bo_v,
    float& q1o, float& q2o, float& q3o,
    float& s11, float& s21, float& s31,
    float& s12, float& s22, float& s32)
{
  // ---- first layer (f32x2 pairs, per-lane = per-sample): h and u packs ----
  unsigned int hp[32], up[32];
#pragma unroll
  for (int d = 0; d < 32; ++d){
    f32x2 w0a = *(const f32x2*)(W0 + 2*d);
    f32x2 w0b = *(const f32x2*)(W0 + 64 + 2*d);
    f32x2 b0v = *(const f32x2*)(b0 + 2*d);
    f32x2 pre = y2 * w0a + (y3 * w0b + b0v);      // v_pk_fma_f32 x2
    float hA = fast_tanh(pre.x), hB = fast_tanh(pre.y);
    f32x2 h  = {hA, hB};
    f32x2 u  = 1.0f - h * h;
    hp[d] = pack2bf(hA, hB);
    up[d] = pack2bf(u.x, u.y);
  }

  float qraw[3] = {0,0,0}, Araw[3] = {0,0,0}, Braw[3] = {0,0,0};
  const int bsw = (colL & 7) << 4;

#pragma unroll 1
  for (int st = 0; st < 4; ++st){
    // stage this tile in-place (same-wave program order -> overwrite safe)
    stage_tile(sAw, st, grp, colL, hp, up);

    // sample-column fragments for this tile (B-operand)
    bf16x8 afh[2], afu[2];
#pragma unroll
    for (int kt = 0; kt < 2; ++kt){
      int off = colL*128 + ((kt*64 + grp*16) ^ bsw);
      afh[kt] = *(const bf16x8*)(sAw + off);
      afu[kt] = *(const bf16x8*)(sAw + 2048 + off);
    }

#pragma unroll
    for (int hd = 0; hd < 3; ++hd){
      float aq = 0.0f, aA = 0.0f, aB = 0.0f;
#pragma unroll
      for (int nt = 0; nt < 2; ++nt){
        // B-matrix fragments (A-operand) from LDS at point of use
        bf16x8 bW[2], bA[2], bB[2];
#pragma unroll
        for (int kt = 0; kt < 2; ++kt){
          int rbase2 = (hd*96 + nt*16 + colL) * 128;
          int ko = ((kt*64 + grp*16) ^ bsw);
          bW[kt] = *(const bf16x8*)(sBb + rbase2 + ko);
          bA[kt] = *(const bf16x8*)(sBb + rbase2 + 4096 + ko);
          bB[kt] = *(const bf16x8*)(sBb + rbase2 + 8192 + ko);
        }
        // this lane's 4 n-rows: n = nt*16 + grp*4 + r
        f32x4 bh4 = *(const f32x4*)(sBH + hd*32 + nt*16 + grp*4);
        f32x4 wo4 = *(const f32x4*)(sWO + hd*32 + nt*16 + grp*4);
        f32x4 cAT = bh4;                     // bh folded in via C-seed
        f32x4 cA2 = {0,0,0,0}, cA3 = {0,0,0,0};
#pragma unroll
        for (int kt = 0; kt < 2; ++kt){
          cAT = __builtin_amdgcn_mfma_f32_16x16x32_bf16(bW[kt], afh[kt], cAT, 0, 0, 0);
          cA2 = __builtin_amdgcn_mfma_f32_16x16x32_bf16(bA[kt], afu[kt], cA2, 0, 0, 0);
          cA3 = __builtin_amdgcn_mfma_f32_16x16x32_bf16(bB[kt], afu[kt], cA3, 0, 0, 0);
        }
        float t0 = fast_tanh(cAT[0]);
        float t1 = fast_tanh(cAT[1]);
        float t2 = fast_tanh(cAT[2]);
        float t3 = fast_tanh(cAT[3]);
        // q-path: wo in f32 (tanh blocks folding)
        aq = fmaf(t0, wo4[0], aq);
        aq = fmaf(t1, wo4[1], aq);
        aq = fmaf(t2, wo4[2], aq);
        aq = fmaf(t3, wo4[3], aq);
        // JVP paths: wo*SIG pre-folded into the B matrices
        float dt0 = fmaf(-t0, t0, 1.0f);
        float dt1 = fmaf(-t1, t1, 1.0f);
        float dt2 = fmaf(-t2, t2, 1.0f);
        float dt3 = fmaf(-t3, t3, 1.0f);
        aA = fmaf(dt0, cA2[0], aA);
        aA = fmaf(dt1, cA2[1], aA);
        aA = fmaf(dt2, cA2[2], aA);
        aA = fmaf(dt3, cA2[3], aA);
        aB = fmaf(dt0, cA3[0], aB);
        aB = fmaf(dt1, cA3[1], aB);
        aB = fmaf(dt2, cA3[2], aB);
        aB = fmaf(dt3, cA3[3], aB);
      }
      // cross-group reduce: n also spans the 4 lane-groups
      aq += __shfl_xor(aq, 16, 64);  aq += __shfl_xor(aq, 32, 64);
      aA += __shfl_xor(aA, 16, 64);  aA += __shfl_xor(aA, 32, 64);
      aB += __shfl_xor(aB, 16, 64);  aB += __shfl_xor(aB, 32, 64);
      // after butterfly every lane holds sample (st*16+colL)'s sum;
      // lane owns sample (grp*16+colL) -> keep when st == grp
      bool keep = (st == grp);
      qraw[hd] = keep ? aq : qraw[hd];
      Araw[hd] = keep ? aA : Araw[hd];
      Braw[hd] = keep ? aB : Braw[hd];
    }
  }

  q1o = __expf(qraw[0] + bo_v[0]);
  q2o = __expf(qraw[1] + bo_v[1]);
  q3o = __expf(qraw[2] + bo_v[2]);
  s11 = Araw[0]; s21 = Araw[1]; s31 = Araw[2];   // SIG folded into B
  s12 = Braw[0]; s22 = Braw[1]; s32 = Braw[2];
}

// NOTE: no min-waves __launch_bounds__ arg — it forces accumulator spills
// ((256,3)->210GB, (256,4)->42GB scratch writes). Natural allocation is clean.
__global__ __launch_bounds__(NB)
void sim_kernel(const float* __restrict__ Y,
  const float* __restrict__ W0,  const float* __restrict__ b0,
  const float* __restrict__ Wh1, const float* __restrict__ bh1,
  const float* __restrict__ Wo1, const float* __restrict__ bo1,
  const float* __restrict__ Wh2, const float* __restrict__ bh2,
  const float* __restrict__ Wo2, const float* __restrict__ bo2,
  const float* __restrict__ Wh3, const float* __restrict__ bh3,
  const float* __restrict__ Wo3, const float* __restrict__ bo3,
  float* __restrict__ out, int n)
{
  // B matrices: per head {Wh^T, (diag(w0a)Wh diag(wo*SIG))^T,
  // (diag(w0b)Wh diag(wo*SIG))^T}, bf16, swizzled 128B rows. 288 rows = 36 KB.
  __shared__ __align__(16) char sB[288 * 128];
  __shared__ __align__(16) char sA[4][2 * 16 * 128];   // per-wave {h,u} (16 KB)
  __shared__ __align__(16) float sBH[96];              // bh per head/n (f32)
  __shared__ __align__(16) float sWO[96];              // wo per head/n (f32)

  for (int e = threadIdx.x; e < 18432; e += NB){
    int hd   = e / 6144;
    int rem  = e - hd * 6144;
    int mat  = rem >> 11;          // 0=Wh, 1=w0a-scaled, 2=w0b-scaled
    int rem2 = rem & 2047;
    int j = rem2 >> 5, i = rem2 & 31;
    const float* W  = (hd == 0) ? Wh1 : (hd == 1) ? Wh2 : Wh3;
    const float* WO = (hd == 0) ? Wo1 : (hd == 1) ? Wo2 : Wo3;
    float wh = W[j * 32 + i];
    float sc = WO[i] * 0.03f;      // wo * SIGMA fold (JVP mats only)
    float v  = (mat == 0) ? wh
             : (mat == 1) ? W0[j] * wh * sc
                          : W0[64 + j] * wh * sc;
    int R   = hd * 96 + mat * 32 + i;
    int off = (R * 128 + j * 2) ^ ((R & 7) << 4);
    *(unsigned short*)(sB + off) = (unsigned short)f2bfbits(v);
  }
  if (threadIdx.x < 96){
    int hd = threadIdx.x >> 5, row = threadIdx.x & 31;
    const float* BH = (hd == 0) ? bh1 : (hd == 1) ? bh2 : bh3;
    const float* WO = (hd == 0) ? Wo1 : (hd == 1) ? Wo2 : Wo3;
    sBH[threadIdx.x] = BH[row];
    sWO[threadIdx.x] = WO[row];
  }
  __syncthreads();

  const int wv   = threadIdx.x >> 6;
  const int lane = threadIdx.x & 63;
  const int colL = lane & 15;
  const int grp  = lane >> 4;
  char* sAw = &sA[wv][0];

  float bo_v[3] = {bo1[0], bo2[0], bo3[0]};

  const int gid = blockIdx.x * NB + threadIdx.x;
  const int ii  = (gid < n) ? gid : (n - 1);
  const float valid = (gid < n) ? 1.0f : 0.0f;

  const float2 yv = ((const float2*)Y)[ii];
  const float y2 = yv.x, y3 = yv.y;

  const float GAMMA = 1.2f, DT = 0.005f, SIGMA = 0.03f;
  const float KAPPA = 0.2f, YBAR = 2.0f, RHO = 0.03f, Bc = 1.0f, Cc = 0.1f;

  float q1,q2,q3,s11,s21,s31,s12,s22,s32;
  net_eval(y2, y3, W0, b0, sAw, sB, sBH, sWO, colL, grp, bo_v,
           q1,q2,q3,s11,s21,s31,s12,s22,s32);
  float Y2 = y2, Y3 = y3;
  float loss = 0.0f;

  for (int t = 0; t < PERIOD; ++t){
    // --- noise: threefry rollout, counter = flat index (bit-exact) ---
    uint32_t idx0 = 2u * ((uint32_t)t * (uint32_t)n + (uint32_t)ii);
    uint32_t a0, a1, c0, c1;
    threefry2x32_k42(0u, idx0,      a0, a1);
    threefry2x32_k42(0u, idx0 + 1u, c0, c1);
    float dZ1 = 0.070710678f * normal_from_bits(a0 ^ a1);
    float dZ2 = 0.070710678f * normal_from_bits(c0 ^ c1);

    // --- step math (mirror reference, f32) ---
    float Wt  = q1 + q2 + q3;
    float q1h = q1 / Wt;
    float q2h = q2 / Wt;
    float q3h = 1.0f - q1h - q2h;
    float q1sq = q1 * q1;
    float c   = Bc*q1 - Cc*q1sq + Y2 + Y3;
    float bq  = Bc*q1 - 2.0f*Cc*q1sq;
    float sc1 = fmaf(bq, s11, SIGMA);
    float sc2 = fmaf(bq, s12, SIGMA);
    float sW1 = q1*s11 + q2*s21 + q3*s31;
    float sW2 = q1*s12 + q2*s22 + q3*s32;
    float sJ1 = 6.0f * (sc1/c - sW1/Wt);
    float sJ2 = 6.0f * (sc2/c - sW2/Wt);
    float d11 = s11*s11 + s12*s12;
    float d12 = s11*s21 + s12*s22;
    float d13 = s11*s31 + s12*s32;
    float d22 = s21*s21 + s22*s22;
    float d23 = s21*s31 + s22*s32;
    float d33 = s31*s31 + s32*s32;
    const float oneMG = 1.0f - GAMMA;   // -0.2
    float p1 = GAMMA*(q1h*d11 + q2h*d12 + q3h*d13) - oneMG*(sJ1*s11 + sJ2*s12);
    float p2 = GAMMA*(q1h*d12 + q2h*d22 + q3h*d23) - oneMG*(sJ1*s21 + sJ2*s22);
    float p3 = GAMMA*(q1h*d13 + q2h*d23 + q3h*d33) - oneMG*(sJ1*s31 + sJ2*s32);
    float muY2 = KAPPA * (YBAR - Y2);
    float muY3 = KAPPA * (YBAR - Y3);
    float r = RHO + GAMMA*(bq*(p1 - (Bc - Cc*q1)) - Cc*q1sq*d11 + muY2 + muY3)/c
                  - 1.32f*(sc1*sc1 + sc2*sc2)/(c*c);
    r = r / (1.0f - GAMMA*bq/c);
    float mu1 = r + p1 - (Bc - Cc*q1);
    float mu2 = r + p2 - Y2/q2;
    float mu3 = r + p3 - Y3/q3;
    float q1n = q1 * (1.0f + mu1*DT + s11*dZ1 + s12*dZ2);
    float q2n = q2 * (1.0f + mu2*DT + s21*dZ1 + s22*dZ2);
    float q3n = q3 * (1.0f + mu3*DT + s31*dZ1 + s32*dZ2);
    float Y2n = Y2 + muY2*DT + SIGMA*dZ1;
    float Y3n = Y3 + muY3*DT + SIGMA*dZ2;

    float qt1, qt2, qt3;
    net_eval(Y2n, Y3n, W0, b0, sAw, sB, sBH, sWO, colL, grp, bo_v,
             qt1,qt2,qt3, s11,s21,s31,s12,s22,s32);

    float e1 = q1n - qt1, e2 = q2n - qt2, e3 = q3n - qt3;
    loss += e1*e1 + e2*e2 + e3*e3;

    q1 = q1n; q2 = q2n; q3 = q3n; Y2 = Y2n; Y3 = Y3n;
  }

  loss *= valid * (1.0f / ((float)15000000));   // / (n * PERIOD)

  // --- block reduction -> one atomic per block ---
#pragma unroll
  for (int off = 32; off > 0; off >>= 1)
    loss += __shfl_down(loss, off, 64);
  __shared__ float sred[NB / 64];
  if (lane == 0) sred[wv] = loss;
  __syncthreads();
  if (threadIdx.x == 0){
    float s = 0.0f;
#pragma unroll
    for (int w = 0; w < NB / 64; ++w) s += sred[w];
    atomicAdd(out, s);
  }
}

extern "C" void kernel_launch(void* const* d_in, const int* in_sizes, int n_in,
                              void* d_out, int out_size, void* d_ws, size_t ws_size,
                              hipStream_t stream)
{
  const float* Y   = (const float*)d_in[0];
  const float* W0  = (const float*)d_in[1];
  const float* b0  = (const float*)d_in[2];
  const float* Wh1 = (const float*)d_in[3];
  const float* bh1 = (const float*)d_in[4];
  const float* Wo1 = (const float*)d_in[5];
  const float* bo1 = (const float*)d_in[6];
  const float* Wh2 = (const float*)d_in[7];
  const float* bh2 = (const float*)d_in[8];
  const float* Wo2 = (const float*)d_in[9];
  const float* bo2 = (const float*)d_in[10];
  const float* Wh3 = (const float*)d_in[11];
  const float* bh3 = (const float*)d_in[12];
  const float* Wo3 = (const float*)d_in[13];
  const float* bo3 = (const float*)d_in[14];

  const int n = in_sizes[0] / 2;

  (void)hipMemsetAsync(d_out, 0, sizeof(float), stream);

  const int grid = (n + NB - 1) / NB;
  sim_kernel<<<grid, NB, 0, stream>>>(Y,
      W0, b0, Wh1, bh1, Wo1, bo1, Wh2, bh2, Wo2, bo2, Wh3, bh3, Wo3, bo3,
      (float*)d_out, n);
}